// Round 5
// baseline (982.745 us; speedup 1.0000x reference)
//
#include <hip/hip_runtime.h>
#include <cstdint>

typedef unsigned short u16;
typedef __attribute__((ext_vector_type(8))) short s8v;   // 8 bf16 = one MFMA operand frag
typedef __attribute__((ext_vector_type(4))) float f4v;   // MFMA accumulator / vec loads

__device__ __forceinline__ float bf2f(u16 b) {
  unsigned int u = ((unsigned int)b) << 16;
  float f;
  __builtin_memcpy(&f, &u, 4);
  return f;
}
__device__ __forceinline__ u16 f2bf(float f) {
  unsigned int u;
  __builtin_memcpy(&u, &f, 4);
  u += 0x7fffu + ((u >> 16) & 1u);   // RNE (finite inputs only)
  return (u16)(u >> 16);
}

// async global->LDS, 16B per lane; LDS dest = wave-uniform base + lane*16
__device__ __forceinline__ void glds16(const void* g, void* l) {
  __builtin_amdgcn_global_load_lds(
      (const __attribute__((address_space(1))) unsigned int*)g,
      (__attribute__((address_space(3))) unsigned int*)l, 16, 0, 0);
}

#define BM 128
#define BN 128
#define BK 32

// ---------------- dtype detector ----------------
// flg[0]=1: fp32 storage, 0: bf16.  Also zero-inits flg[1] (input lo!=0), flg[2] (weight lo!=0).
__global__ __launch_bounds__(256)
void detect_dtype(const u16* __restrict__ q, int* __restrict__ flg)
{
  __shared__ int cbig, czero;
  if (threadIdx.x == 0) { cbig = 0; czero = 0; }
  __syncthreads();
  int b = 0, z = 0;
  for (int i = threadIdx.x; i < 4096; i += 256) {
    float v = bf2f(q[i]);
    if (!(fabsf(v) < 1e4f)) b++;
    if ((i & 1) == 0 && q[i] == 0) z++;
  }
  atomicAdd(&cbig, b);
  atomicAdd(&czero, z);
  __syncthreads();
  if (threadIdx.x == 0) {
    flg[0] = (cbig > 64 || czero > 1600) ? 1 : 0;
    flg[1] = 0;
    flg[2] = 0;
  }
}

// ---------------- inputs -> hi/lo planes (query & kv in one launch, z selects) ----------------
__global__ __launch_bounds__(256)
void convert_hl2(const int* __restrict__ flg,
                 const void* __restrict__ q, const void* __restrict__ kv,
                 u16* __restrict__ qh, u16* __restrict__ ql,
                 u16* __restrict__ kvh, u16* __restrict__ kvl,
                 int* __restrict__ lo_flag, long n)
{
  const void* in = blockIdx.y ? kv : q;
  u16* hi = blockIdx.y ? kvh : qh;
  u16* lo = blockIdx.y ? kvl : ql;
  const long i = ((long)blockIdx.x * 256 + threadIdx.x) * 8;
  if (i >= n) return;
  s8v h, l;
  bool lnz = false;
  if (flg[0] != 0) {
    const float* p = (const float*)in + i;
    f4v f0 = *(const f4v*)p;
    f4v f1 = *(const f4v*)(p + 4);
#pragma unroll
    for (int j = 0; j < 4; ++j) {
      u16 hh;
      hh = f2bf(f0[j]); h[j]     = (short)hh; l[j]     = (short)f2bf(f0[j] - bf2f(hh));
      hh = f2bf(f1[j]); h[4 + j] = (short)hh; l[4 + j] = (short)f2bf(f1[j] - bf2f(hh));
    }
#pragma unroll
    for (int j = 0; j < 8; ++j) lnz |= (l[j] != 0);
  } else {
    h = *(const s8v*)((const short*)in + i);
#pragma unroll
    for (int j = 0; j < 8; ++j) l[j] = 0;
  }
  *(s8v*)(hi + i) = h;
  *(s8v*)(lo + i) = l;
  unsigned long long m = __ballot(lnz);
  if ((threadIdx.x & 63) == 0 && m) atomicOr(lo_flag, 1);
}

// ---------------- all four W^T in one launch (z selects); lo planes for z<2 ----------------
__global__ __launch_bounds__(256)
void transpose_w4(const int* __restrict__ flg,
                  const void* __restrict__ w0, const void* __restrict__ w1,
                  const void* __restrict__ w2, const void* __restrict__ w3,
                  u16* __restrict__ h0, u16* __restrict__ h1,
                  u16* __restrict__ h2, u16* __restrict__ h3,
                  u16* __restrict__ l0, u16* __restrict__ l1,
                  int* __restrict__ lo_flag, int D)
{
  __shared__ float tile[32][33];
  const int zb = blockIdx.z;
  const void* in_v = (zb == 0) ? w0 : (zb == 1) ? w1 : (zb == 2) ? w2 : w3;
  u16* outH = (zb == 0) ? h0 : (zb == 1) ? h1 : (zb == 2) ? h2 : h3;
  u16* outL = (zb == 0) ? l0 : (zb == 1) ? l1 : nullptr;
  const bool i32 = (flg[0] != 0);
  const u16*   in16 = (const u16*)in_v;
  const float* in32 = (const float*)in_v;
  const int c0 = blockIdx.x * 32, r0 = blockIdx.y * 32;
  const int tx = threadIdx.x, ty = threadIdx.y;   // block (32,8)
  for (int i = ty; i < 32; i += 8) {
    const long idx = (long)(r0 + i) * D + c0 + tx;
    tile[i][tx] = i32 ? in32[idx] : bf2f(in16[idx]);
  }
  __syncthreads();
  bool lnz = false;
  for (int i = ty; i < 32; i += 8) {
    const long idx = (long)(c0 + i) * D + r0 + tx;
    const float v = tile[tx][i];
    const u16 h = f2bf(v);
    outH[idx] = h;
    const u16 l = f2bf(v - bf2f(h));
    if (outL) { outL[idx] = l; lnz |= (l != 0); }
    else      { lnz |= (l != 0); }   // Wv/Wo lo dropped; still contributes to flag? no:
  }
  // only Wq/Wk lo planes feed the fast-path decision; Wv/Wo are bf16-rounded regardless.
  if (zb < 2) {
    unsigned long long m = __ballot(lnz);
    if (((ty * 32 + tx) & 63) == 0 && m) atomicOr(lo_flag, 1);
  }
}

// ---------------- plain bf16 NT GEMM, m97 structure ----------------
// OUT_FLAG: true -> fp32 if flg[0] else bf16; false -> bf16.
template<bool OUT_FLAG, bool HAS_BIAS>
__global__ __launch_bounds__(256)
void gemm16(const int* __restrict__ flg, const u16* __restrict__ A,
            const u16* __restrict__ Bt, const void* __restrict__ bias,
            void* __restrict__ Cv, int M, int N, int K,
            long sA, long sB, long sC)
{
  __shared__ u16 As[BM * BK];
  __shared__ u16 Bs[BN * BK];

  const int f_in = flg[0];
  const int tid = threadIdx.x, lane = tid & 63, wave = tid >> 6;
  const int wm = wave >> 1, wn = wave & 1;
  const int m0 = blockIdx.y * BM, n0 = blockIdx.x * BN;
  const long z = blockIdx.z;
  const u16* Ap = A + z * sA;
  const u16* Bp = Bt + z * sB;

  const int rr  = wave * 32 + (lane >> 2);
  const int cc8 = (lane & 3) * 8;
  const u16* ga0 = Ap + (long)(m0 + rr) * K + cc8;
  const u16* ga1 = ga0 + 16 * (long)K;
  const u16* gb0 = Bp + (long)(n0 + rr) * K + cc8;
  const u16* gb1 = gb0 + 16 * (long)K;
  u16* la0 = &As[(wave * 2    ) * 512];
  u16* la1 = &As[(wave * 2 + 1) * 512];
  u16* lb0 = &Bs[(wave * 2    ) * 512];
  u16* lb1 = &Bs[(wave * 2 + 1) * 512];

  f4v acc[4][4];
#pragma unroll
  for (int i = 0; i < 4; ++i)
#pragma unroll
    for (int j = 0; j < 4; ++j) acc[i][j] = (f4v){0.f, 0.f, 0.f, 0.f};

  const int fr = lane & 15, fk = (lane >> 4) * 8;
  const int aoff = (wm * 64 + fr) * BK + fk;
  const int boff = (wn * 64 + fr) * BK + fk;

  for (int kt = 0; kt < K; kt += BK) {
    glds16(ga0, la0); glds16(ga1, la1);
    glds16(gb0, lb0); glds16(gb1, lb1);
    ga0 += BK; ga1 += BK; gb0 += BK; gb1 += BK;
    __syncthreads();

    s8v af[4], bfr[4];
#pragma unroll
    for (int mi = 0; mi < 4; ++mi) af[mi]  = *(const s8v*)&As[aoff + mi * 16 * BK];
#pragma unroll
    for (int ni = 0; ni < 4; ++ni) bfr[ni] = *(const s8v*)&Bs[boff + ni * 16 * BK];
#pragma unroll
    for (int mi = 0; mi < 4; ++mi)
#pragma unroll
      for (int ni = 0; ni < 4; ++ni)
        acc[mi][ni] = __builtin_amdgcn_mfma_f32_16x16x32_bf16(af[mi], bfr[ni], acc[mi][ni], 0, 0, 0);
    __syncthreads();
  }

  const int cr = (lane >> 4) * 4, ccl = lane & 15;
  const bool o32 = OUT_FLAG && (f_in != 0);
#pragma unroll
  for (int ni = 0; ni < 4; ++ni) {
    const int gcol = n0 + wn * 64 + ni * 16 + ccl;
    float bv = 0.f;
    if (HAS_BIAS)
      bv = (f_in != 0) ? ((const float*)bias)[gcol] : bf2f(((const u16*)bias)[gcol]);
#pragma unroll
    for (int mi = 0; mi < 4; ++mi)
#pragma unroll
      for (int r = 0; r < 4; ++r) {
        const long grow = (long)(m0 + wm * 64 + mi * 16 + cr + r);
        const float val = acc[mi][ni][r] + bv;
        const long idx = z * sC + grow * N + gcol;
        if (o32) ((float*)Cv)[idx] = val;
        else     ((u16*)Cv)[idx]   = f2bf(val);
      }
  }
}

// ---------------- projection GEMM with dynamic precision fast path ----------------
// C = (Ah+Al)*(Bh+Bl)^T + bias -> hi/lo planes.  If flg[1]==0 && flg[2]==0 the lo
// planes are identically zero -> 1-MFMA hh-only loop (numerically exact), else 3-MFMA split.
__global__ __launch_bounds__(256)
void gemm16s_proj(const int* __restrict__ flg,
                  const u16* __restrict__ Ah, const u16* __restrict__ Al,
                  const u16* __restrict__ Bh, const u16* __restrict__ Bl,
                  const void* __restrict__ bias,
                  u16* __restrict__ outH, u16* __restrict__ outL,
                  int M, int N, int K)
{
  __shared__ u16 AsH[BM * BK];
  __shared__ u16 AsL[BM * BK];
  __shared__ u16 BsH[BN * BK];
  __shared__ u16 BsL[BN * BK];

  const int f_in = flg[0];
  const bool fast = (flg[1] == 0) && (flg[2] == 0);
  const int tid = threadIdx.x, lane = tid & 63, wave = tid >> 6;
  const int wm = wave >> 1, wn = wave & 1;
  const int m0 = blockIdx.y * BM, n0 = blockIdx.x * BN;

  const int rr  = wave * 32 + (lane >> 2);
  const int cc8 = (lane & 3) * 8;
  const long ofsA0 = (long)(m0 + rr) * K + cc8;
  const long ofsB0 = (long)(n0 + rr) * K + cc8;
  const u16* gah0 = Ah + ofsA0;  const u16* gah1 = gah0 + 16 * (long)K;
  const u16* gal0 = Al + ofsA0;  const u16* gal1 = gal0 + 16 * (long)K;
  const u16* gbh0 = Bh + ofsB0;  const u16* gbh1 = gbh0 + 16 * (long)K;
  const u16* gbl0 = Bl + ofsB0;  const u16* gbl1 = gbl0 + 16 * (long)K;
  u16* lah0 = &AsH[(wave * 2) * 512];  u16* lah1 = lah0 + 512;
  u16* lal0 = &AsL[(wave * 2) * 512];  u16* lal1 = lal0 + 512;
  u16* lbh0 = &BsH[(wave * 2) * 512];  u16* lbh1 = lbh0 + 512;
  u16* lbl0 = &BsL[(wave * 2) * 512];  u16* lbl1 = lbl0 + 512;

  f4v acc[4][4];
#pragma unroll
  for (int i = 0; i < 4; ++i)
#pragma unroll
    for (int j = 0; j < 4; ++j) acc[i][j] = (f4v){0.f, 0.f, 0.f, 0.f};

  const int fr = lane & 15, fk = (lane >> 4) * 8;
  const int aoff = (wm * 64 + fr) * BK + fk;
  const int boff = (wn * 64 + fr) * BK + fk;

  if (fast) {
    for (int kt = 0; kt < K; kt += BK) {
      glds16(gah0, lah0); glds16(gah1, lah1);
      glds16(gbh0, lbh0); glds16(gbh1, lbh1);
      gah0 += BK; gah1 += BK; gbh0 += BK; gbh1 += BK;
      __syncthreads();
      s8v af[4], bfr[4];
#pragma unroll
      for (int mi = 0; mi < 4; ++mi) af[mi]  = *(const s8v*)&AsH[aoff + mi * 16 * BK];
#pragma unroll
      for (int ni = 0; ni < 4; ++ni) bfr[ni] = *(const s8v*)&BsH[boff + ni * 16 * BK];
#pragma unroll
      for (int mi = 0; mi < 4; ++mi)
#pragma unroll
        for (int ni = 0; ni < 4; ++ni)
          acc[mi][ni] = __builtin_amdgcn_mfma_f32_16x16x32_bf16(af[mi], bfr[ni], acc[mi][ni], 0, 0, 0);
      __syncthreads();
    }
  } else {
    for (int kt = 0; kt < K; kt += BK) {
      glds16(gah0, lah0); glds16(gah1, lah1);
      glds16(gal0, lal0); glds16(gal1, lal1);
      glds16(gbh0, lbh0); glds16(gbh1, lbh1);
      glds16(gbl0, lbl0); glds16(gbl1, lbl1);
      gah0 += BK; gah1 += BK; gal0 += BK; gal1 += BK;
      gbh0 += BK; gbh1 += BK; gbl0 += BK; gbl1 += BK;
      __syncthreads();
      s8v ah[4], al[4], bh[4], bl[4];
#pragma unroll
      for (int mi = 0; mi < 4; ++mi) {
        ah[mi] = *(const s8v*)&AsH[aoff + mi * 16 * BK];
        al[mi] = *(const s8v*)&AsL[aoff + mi * 16 * BK];
      }
#pragma unroll
      for (int ni = 0; ni < 4; ++ni) {
        bh[ni] = *(const s8v*)&BsH[boff + ni * 16 * BK];
        bl[ni] = *(const s8v*)&BsL[boff + ni * 16 * BK];
      }
#pragma unroll
      for (int mi = 0; mi < 4; ++mi)
#pragma unroll
        for (int ni = 0; ni < 4; ++ni) {
          acc[mi][ni] = __builtin_amdgcn_mfma_f32_16x16x32_bf16(ah[mi], bh[ni], acc[mi][ni], 0, 0, 0);
          acc[mi][ni] = __builtin_amdgcn_mfma_f32_16x16x32_bf16(ah[mi], bl[ni], acc[mi][ni], 0, 0, 0);
          acc[mi][ni] = __builtin_amdgcn_mfma_f32_16x16x32_bf16(al[mi], bh[ni], acc[mi][ni], 0, 0, 0);
        }
      __syncthreads();
    }
  }

  const int cr = (lane >> 4) * 4, ccl = lane & 15;
#pragma unroll
  for (int ni = 0; ni < 4; ++ni) {
    const int gcol = n0 + wn * 64 + ni * 16 + ccl;
    const float bv = (f_in != 0) ? ((const float*)bias)[gcol]
                                 : bf2f(((const u16*)bias)[gcol]);
#pragma unroll
    for (int mi = 0; mi < 4; ++mi)
#pragma unroll
      for (int r = 0; r < 4; ++r) {
        const long grow = (long)(m0 + wm * 64 + mi * 16 + cr + r);
        const float val = acc[mi][ni][r] + bv;
        const long idx = grow * N + gcol;
        const u16 h = f2bf(val);
        outH[idx] = h;
        outL[idx] = f2bf(val - bf2f(h));
      }
  }
}

// ---------------- scores GEMM: always 3-MFMA split, fp32 out ----------------
__global__ __launch_bounds__(256)
void gemm16s3(const u16* __restrict__ Ah, const u16* __restrict__ Al,
              const u16* __restrict__ Bh, const u16* __restrict__ Bl,
              float* __restrict__ C, int M, int N, int K,
              long sA, long sB, long sC)
{
  __shared__ u16 AsH[BM * BK];
  __shared__ u16 AsL[BM * BK];
  __shared__ u16 BsH[BN * BK];
  __shared__ u16 BsL[BN * BK];

  const int tid = threadIdx.x, lane = tid & 63, wave = tid >> 6;
  const int wm = wave >> 1, wn = wave & 1;
  const int m0 = blockIdx.y * BM, n0 = blockIdx.x * BN;
  const long z = blockIdx.z;

  const int rr  = wave * 32 + (lane >> 2);
  const int cc8 = (lane & 3) * 8;
  const long ofsA0 = (long)(m0 + rr) * K + cc8 + z * sA;
  const long ofsB0 = (long)(n0 + rr) * K + cc8 + z * sB;
  const u16* gah0 = Ah + ofsA0;  const u16* gah1 = gah0 + 16 * (long)K;
  const u16* gal0 = Al + ofsA0;  const u16* gal1 = gal0 + 16 * (long)K;
  const u16* gbh0 = Bh + ofsB0;  const u16* gbh1 = gbh0 + 16 * (long)K;
  const u16* gbl0 = Bl + ofsB0;  const u16* gbl1 = gbl0 + 16 * (long)K;
  u16* lah0 = &AsH[(wave * 2) * 512];  u16* lah1 = lah0 + 512;
  u16* lal0 = &AsL[(wave * 2) * 512];  u16* lal1 = lal0 + 512;
  u16* lbh0 = &BsH[(wave * 2) * 512];  u16* lbh1 = lbh0 + 512;
  u16* lbl0 = &BsL[(wave * 2) * 512];  u16* lbl1 = lbl0 + 512;

  f4v acc[4][4];
#pragma unroll
  for (int i = 0; i < 4; ++i)
#pragma unroll
    for (int j = 0; j < 4; ++j) acc[i][j] = (f4v){0.f, 0.f, 0.f, 0.f};

  const int fr = lane & 15, fk = (lane >> 4) * 8;
  const int aoff = (wm * 64 + fr) * BK + fk;
  const int boff = (wn * 64 + fr) * BK + fk;

  for (int kt = 0; kt < K; kt += BK) {
    glds16(gah0, lah0); glds16(gah1, lah1);
    glds16(gal0, lal0); glds16(gal1, lal1);
    glds16(gbh0, lbh0); glds16(gbh1, lbh1);
    glds16(gbl0, lbl0); glds16(gbl1, lbl1);
    gah0 += BK; gah1 += BK; gal0 += BK; gal1 += BK;
    gbh0 += BK; gbh1 += BK; gbl0 += BK; gbl1 += BK;
    __syncthreads();

    s8v ah[4], al[4], bh[4], bl[4];
#pragma unroll
    for (int mi = 0; mi < 4; ++mi) {
      ah[mi] = *(const s8v*)&AsH[aoff + mi * 16 * BK];
      al[mi] = *(const s8v*)&AsL[aoff + mi * 16 * BK];
    }
#pragma unroll
    for (int ni = 0; ni < 4; ++ni) {
      bh[ni] = *(const s8v*)&BsH[boff + ni * 16 * BK];
      bl[ni] = *(const s8v*)&BsL[boff + ni * 16 * BK];
    }
#pragma unroll
    for (int mi = 0; mi < 4; ++mi)
#pragma unroll
      for (int ni = 0; ni < 4; ++ni) {
        acc[mi][ni] = __builtin_amdgcn_mfma_f32_16x16x32_bf16(ah[mi], bh[ni], acc[mi][ni], 0, 0, 0);
        acc[mi][ni] = __builtin_amdgcn_mfma_f32_16x16x32_bf16(ah[mi], bl[ni], acc[mi][ni], 0, 0, 0);
        acc[mi][ni] = __builtin_amdgcn_mfma_f32_16x16x32_bf16(al[mi], bh[ni], acc[mi][ni], 0, 0, 0);
      }
    __syncthreads();
  }

  const int cr = (lane >> 4) * 4, ccl = lane & 15;
#pragma unroll
  for (int ni = 0; ni < 4; ++ni) {
    const int gcol = n0 + wn * 64 + ni * 16 + ccl;
#pragma unroll
    for (int mi = 0; mi < 4; ++mi)
#pragma unroll
      for (int r = 0; r < 4; ++r) {
        const long grow = (long)(m0 + wm * 64 + mi * 16 + cr + r);
        C[z * sC + grow * N + gcol] = acc[mi][ni][r];
      }
  }
}

// ---------------- V^T (bf16 in -> bf16 out) ----------------
__global__ __launch_bounds__(256)
void transpose_v(const u16* __restrict__ in, u16* __restrict__ out,
                 int R, int C, long sIn, long sOut)
{
  __shared__ u16 tile[32][33];
  in  += (long)blockIdx.z * sIn;
  out += (long)blockIdx.z * sOut;
  const int c0 = blockIdx.x * 32, r0 = blockIdx.y * 32;
  const int tx = threadIdx.x, ty = threadIdx.y;   // block (32,8)
  for (int i = ty; i < 32; i += 8)
    tile[i][tx] = in[(long)(r0 + i) * C + c0 + tx];
  __syncthreads();
  for (int i = ty; i < 32; i += 8)
    out[(long)(c0 + i) * R + r0 + tx] = tile[tx][i];
}

// ---------------- row softmax fp32 -> bf16 attn, N=2048, one block/row ----------------
__global__ __launch_bounds__(256)
void softmax_rows_bf(const float* __restrict__ S, u16* __restrict__ P, int N)
{
  const float* row = S + (long)blockIdx.x * N;
  u16* prow = P + (long)blockIdx.x * N;
  const int t = threadIdx.x;
  f4v v0 = *(const f4v*)(row + t * 8);
  f4v v1 = *(const f4v*)(row + t * 8 + 4);

  float m = v0[0];
#pragma unroll
  for (int j = 1; j < 4; ++j) m = fmaxf(m, v0[j]);
#pragma unroll
  for (int j = 0; j < 4; ++j) m = fmaxf(m, v1[j]);
  for (int off = 32; off > 0; off >>= 1) m = fmaxf(m, __shfl_down(m, off, 64));

  __shared__ float redm[4], reds[4];
  if ((t & 63) == 0) redm[t >> 6] = m;
  __syncthreads();
  m = fmaxf(fmaxf(redm[0], redm[1]), fmaxf(redm[2], redm[3]));

  float s = 0.f;
#pragma unroll
  for (int j = 0; j < 4; ++j) { v0[j] = __expf(v0[j] - m); s += v0[j]; }
#pragma unroll
  for (int j = 0; j < 4; ++j) { v1[j] = __expf(v1[j] - m); s += v1[j]; }
  for (int off = 32; off > 0; off >>= 1) s += __shfl_down(s, off, 64);
  if ((t & 63) == 0) reds[t >> 6] = s;
  __syncthreads();
  s = reds[0] + reds[1] + reds[2] + reds[3];

  const float inv = 1.f / s;
  s8v o;
#pragma unroll
  for (int j = 0; j < 4; ++j) {
    o[j]     = (short)f2bf(v0[j] * inv);
    o[4 + j] = (short)f2bf(v1[j] * inv);
  }
  *(s8v*)(prow + t * 8) = o;
}

extern "C" void kernel_launch(void* const* d_in, const int* in_sizes, int n_in,
                              void* d_out, int out_size, void* d_ws, size_t ws_size,
                              hipStream_t stream)
{
  const void* query = d_in[0];
  const void* kv    = d_in[1];
  const void* Wq    = d_in[2];
  const void* bq    = d_in[3];
  const void* Wk    = d_in[4];
  const void* bk    = d_in[5];
  const void* Wv    = d_in[6];
  const void* bv    = d_in[7];
  const void* Wo    = d_in[8];
  const void* bo    = d_in[9];

  const int Bn = 4, S = 2048, D = 1024;
  const int MS = Bn * S;                       // 8192
  const size_t KBu = 1024, MBu = 1024 * 1024;
  const long nTok = (long)MS * D;              // 8388608 elems

  // ---- workspace layout (total ~172.1 MB) ----
  char* ws = (char*)d_ws;
  int*   flg  = (int*)(ws);                    // [0]=dtype, [1]=input lo!=0, [2]=W lo!=0
  char*  rA   = ws + 64 * KBu;                 // 64MB: input planes, later Sc
  u16*   Qih  = (u16*)(rA);
  u16*   Qil  = (u16*)(rA + 16 * MBu);
  u16*   KVh  = (u16*)(rA + 32 * MBu);
  u16*   KVl  = (u16*)(rA + 48 * MBu);
  float* Sc   = (float*)(rA);                  // 64MB fp32 scores (inputs dead by then)
  char*  rW   = rA + 64 * MBu;                 // 12MB: W^T planes
  u16*   WqTh = (u16*)(rW);
  u16*   WqTl = (u16*)(rW + 2 * MBu);
  u16*   WkTh = (u16*)(rW + 4 * MBu);
  u16*   WkTl = (u16*)(rW + 6 * MBu);
  u16*   WvTh = (u16*)(rW + 8 * MBu);
  u16*   WoTh = (u16*)(rW + 10 * MBu);
  char*  rQK  = rW + 12 * MBu;                 // 64MB: Q/K planes, later attn
  u16*   Qh   = (u16*)(rQK);
  u16*   Ql   = (u16*)(rQK + 16 * MBu);
  u16*   Kh   = (u16*)(rQK + 32 * MBu);
  u16*   Kl   = (u16*)(rQK + 48 * MBu);
  u16*   attn = (u16*)(rQK);                   // 32MB bf16 (Q planes dead after scores)
  char*  rV   = rQK + 64 * MBu;                // 32MB
  u16*   Vb   = (u16*)(rV);                    // dead after V^T
  u16*   Cx   = (u16*)(rV);                    // ctx overlays Vb
  u16*   Vt   = (u16*)(rV + 16 * MBu);

  detect_dtype<<<1, 256, 0, stream>>>((const u16*)query, flg);

  convert_hl2<<<dim3((unsigned)(nTok / 2048), 2), 256, 0, stream>>>(
      flg, query, kv, Qih, Qil, KVh, KVl, flg + 1, nTok);

  dim3 tb(32, 8);
  transpose_w4<<<dim3(32, 32, 4), tb, 0, stream>>>(
      flg, Wq, Wk, Wv, Wo, WqTh, WkTh, WvTh, WoTh, WqTl, WkTl, flg + 2, D);

  // projections: Q,K split planes out (fast 1x path when inputs+weights on bf16 grid)
  gemm16s_proj<<<dim3(D / BN, MS / BM, 1), 256, 0, stream>>>(
      flg, Qih, Qil, WqTh, WqTl, bq, Qh, Ql, MS, D, D);
  gemm16s_proj<<<dim3(D / BN, MS / BM, 1), 256, 0, stream>>>(
      flg, KVh, KVl, WkTh, WkTl, bk, Kh, Kl, MS, D, D);
  gemm16<false, true><<<dim3(D / BN, MS / BM, 1), 256, 0, stream>>>(
      flg, KVh, WvTh, bv, Vb, MS, D, D, 0L, 0L, 0L);

  transpose_v<<<dim3(D / 32, S / 32, Bn), tb, 0, stream>>>(
      Vb, Vt, S, D, (long)S * D, (long)D * S);

  // scores (split 3x, fp32), softmax -> bf16 attn, PV (plain bf16)
  gemm16s3<<<dim3(S / BN, S / BM, Bn), 256, 0, stream>>>(
      Qh, Ql, Kh, Kl, Sc, S, S, D, (long)S * D, (long)S * D, (long)S * S);
  softmax_rows_bf<<<dim3(Bn * S), 256, 0, stream>>>(Sc, attn, S);
  gemm16<false, false><<<dim3(D / BN, S / BM, Bn), 256, 0, stream>>>(
      flg, attn, Vt, nullptr, Cx, S, D, S, (long)S * S, (long)D * S, (long)S * D);

  // output projection -> d_out (dtype per flag)
  gemm16<true, true><<<dim3(D / BN, MS / BM, 1), 256, 0, stream>>>(
      flg, Cx, WoTh, bo, d_out, MS, D, D, 0L, 0L, 0L);
}

// Round 6
// 539.683 us; speedup vs baseline: 1.8210x; 1.8210x over previous
//
#include <hip/hip_runtime.h>
#include <cstdint>

typedef unsigned short u16;
typedef __attribute__((ext_vector_type(8))) short s8v;   // 8 bf16 = one MFMA operand frag
typedef __attribute__((ext_vector_type(4))) float f4v;   // MFMA accumulator / vec loads

__device__ __forceinline__ float bf2f(u16 b) {
  unsigned int u = ((unsigned int)b) << 16;
  float f;
  __builtin_memcpy(&f, &u, 4);
  return f;
}
__device__ __forceinline__ u16 f2bf(float f) {
  unsigned int u;
  __builtin_memcpy(&u, &f, 4);
  u += 0x7fffu + ((u >> 16) & 1u);   // RNE (finite inputs only)
  return (u16)(u >> 16);
}

// async global->LDS, 16B per lane; LDS dest = wave-uniform base + lane*16
__device__ __forceinline__ void glds16(const void* g, void* l) {
  __builtin_amdgcn_global_load_lds(
      (const __attribute__((address_space(1))) unsigned int*)g,
      (__attribute__((address_space(3))) unsigned int*)l, 16, 0, 0);
}

#define BM 128
#define BN 128
#define BK 32

// ---------------- dtype detector (flg[0]=1: fp32 storage, 0: bf16) ----------------
__global__ __launch_bounds__(256)
void detect_dtype(const u16* __restrict__ q, int* __restrict__ flg)
{
  __shared__ int cbig, czero;
  if (threadIdx.x == 0) { cbig = 0; czero = 0; }
  __syncthreads();
  int b = 0, z = 0;
  for (int i = threadIdx.x; i < 4096; i += 256) {
    float v = bf2f(q[i]);
    if (!(fabsf(v) < 1e4f)) b++;
    if ((i & 1) == 0 && q[i] == 0) z++;
  }
  atomicAdd(&cbig, b);
  atomicAdd(&czero, z);
  __syncthreads();
  if (threadIdx.x == 0) flg[0] = (cbig > 64 || czero > 1600) ? 1 : 0;
}

// ---------------- inputs -> hi/lo planes (query & kv in one launch; NO atomics) ----------------
__global__ __launch_bounds__(256)
void convert_hl2(const int* __restrict__ flg,
                 const void* __restrict__ q, const void* __restrict__ kv,
                 u16* __restrict__ qh, u16* __restrict__ ql,
                 u16* __restrict__ kvh, u16* __restrict__ kvl, long n)
{
  const void* in = blockIdx.y ? kv : q;
  u16* hi = blockIdx.y ? kvh : qh;
  u16* lo = blockIdx.y ? kvl : ql;
  const long i = ((long)blockIdx.x * 256 + threadIdx.x) * 8;
  if (i >= n) return;
  s8v h, l;
  if (flg[0] != 0) {
    const float* p = (const float*)in + i;
    f4v f0 = *(const f4v*)p;
    f4v f1 = *(const f4v*)(p + 4);
#pragma unroll
    for (int j = 0; j < 4; ++j) {
      u16 hh;
      hh = f2bf(f0[j]); h[j]     = (short)hh; l[j]     = (short)f2bf(f0[j] - bf2f(hh));
      hh = f2bf(f1[j]); h[4 + j] = (short)hh; l[4 + j] = (short)f2bf(f1[j] - bf2f(hh));
    }
  } else {
    h = *(const s8v*)((const short*)in + i);
#pragma unroll
    for (int j = 0; j < 8; ++j) l[j] = 0;
  }
  *(s8v*)(hi + i) = h;
  *(s8v*)(lo + i) = l;
}

// ---------------- all four W^T in one launch (z selects); lo planes for Wq/Wk ----------------
__global__ __launch_bounds__(256)
void transpose_w4(const int* __restrict__ flg,
                  const void* __restrict__ w0, const void* __restrict__ w1,
                  const void* __restrict__ w2, const void* __restrict__ w3,
                  u16* __restrict__ h0, u16* __restrict__ h1,
                  u16* __restrict__ h2, u16* __restrict__ h3,
                  u16* __restrict__ l0, u16* __restrict__ l1, int D)
{
  __shared__ float tile[32][33];
  const int zb = blockIdx.z;
  const void* in_v = (zb == 0) ? w0 : (zb == 1) ? w1 : (zb == 2) ? w2 : w3;
  u16* outH = (zb == 0) ? h0 : (zb == 1) ? h1 : (zb == 2) ? h2 : h3;
  u16* outL = (zb == 0) ? l0 : (zb == 1) ? l1 : nullptr;
  const bool i32 = (flg[0] != 0);
  const u16*   in16 = (const u16*)in_v;
  const float* in32 = (const float*)in_v;
  const int c0 = blockIdx.x * 32, r0 = blockIdx.y * 32;
  const int tx = threadIdx.x, ty = threadIdx.y;   // block (32,8)
  for (int i = ty; i < 32; i += 8) {
    const long idx = (long)(r0 + i) * D + c0 + tx;
    tile[i][tx] = i32 ? in32[idx] : bf2f(in16[idx]);
  }
  __syncthreads();
  for (int i = ty; i < 32; i += 8) {
    const long idx = (long)(c0 + i) * D + r0 + tx;
    const float v = tile[tx][i];
    const u16 h = f2bf(v);
    outH[idx] = h;
    if (outL) outL[idx] = f2bf(v - bf2f(h));
  }
}

// ---------------- plain bf16 NT GEMM, m97 structure ----------------
// OUT_FLAG: true -> fp32 if flg[0] else bf16; false -> bf16.
template<bool OUT_FLAG, bool HAS_BIAS>
__global__ __launch_bounds__(256)
void gemm16(const int* __restrict__ flg, const u16* __restrict__ A,
            const u16* __restrict__ Bt, const void* __restrict__ bias,
            void* __restrict__ Cv, int M, int N, int K,
            long sA, long sB, long sC)
{
  __shared__ u16 As[BM * BK];
  __shared__ u16 Bs[BN * BK];

  const int f_in = flg[0];
  const int tid = threadIdx.x, lane = tid & 63, wave = tid >> 6;
  const int wm = wave >> 1, wn = wave & 1;
  const int m0 = blockIdx.y * BM, n0 = blockIdx.x * BN;
  const long z = blockIdx.z;
  const u16* Ap = A + z * sA;
  const u16* Bp = Bt + z * sB;

  const int rr  = wave * 32 + (lane >> 2);
  const int cc8 = (lane & 3) * 8;
  const u16* ga0 = Ap + (long)(m0 + rr) * K + cc8;
  const u16* ga1 = ga0 + 16 * (long)K;
  const u16* gb0 = Bp + (long)(n0 + rr) * K + cc8;
  const u16* gb1 = gb0 + 16 * (long)K;
  u16* la0 = &As[(wave * 2    ) * 512];
  u16* la1 = &As[(wave * 2 + 1) * 512];
  u16* lb0 = &Bs[(wave * 2    ) * 512];
  u16* lb1 = &Bs[(wave * 2 + 1) * 512];

  f4v acc[4][4];
#pragma unroll
  for (int i = 0; i < 4; ++i)
#pragma unroll
    for (int j = 0; j < 4; ++j) acc[i][j] = (f4v){0.f, 0.f, 0.f, 0.f};

  const int fr = lane & 15, fk = (lane >> 4) * 8;
  const int aoff = (wm * 64 + fr) * BK + fk;
  const int boff = (wn * 64 + fr) * BK + fk;

  for (int kt = 0; kt < K; kt += BK) {
    glds16(ga0, la0); glds16(ga1, la1);
    glds16(gb0, lb0); glds16(gb1, lb1);
    ga0 += BK; ga1 += BK; gb0 += BK; gb1 += BK;
    __syncthreads();

    s8v af[4], bfr[4];
#pragma unroll
    for (int mi = 0; mi < 4; ++mi) af[mi]  = *(const s8v*)&As[aoff + mi * 16 * BK];
#pragma unroll
    for (int ni = 0; ni < 4; ++ni) bfr[ni] = *(const s8v*)&Bs[boff + ni * 16 * BK];
#pragma unroll
    for (int mi = 0; mi < 4; ++mi)
#pragma unroll
      for (int ni = 0; ni < 4; ++ni)
        acc[mi][ni] = __builtin_amdgcn_mfma_f32_16x16x32_bf16(af[mi], bfr[ni], acc[mi][ni], 0, 0, 0);
    __syncthreads();
  }

  const int cr = (lane >> 4) * 4, ccl = lane & 15;
  const bool o32 = OUT_FLAG && (f_in != 0);
#pragma unroll
  for (int ni = 0; ni < 4; ++ni) {
    const int gcol = n0 + wn * 64 + ni * 16 + ccl;
    float bv = 0.f;
    if (HAS_BIAS)
      bv = (f_in != 0) ? ((const float*)bias)[gcol] : bf2f(((const u16*)bias)[gcol]);
#pragma unroll
    for (int mi = 0; mi < 4; ++mi)
#pragma unroll
      for (int r = 0; r < 4; ++r) {
        const long grow = (long)(m0 + wm * 64 + mi * 16 + cr + r);
        const float val = acc[mi][ni][r] + bv;
        const long idx = z * sC + grow * N + gcol;
        if (o32) ((float*)Cv)[idx] = val;
        else     ((u16*)Cv)[idx]   = f2bf(val);
      }
  }
}

// ---------------- V-projection with fused transposed epilogue ----------------
// C = A*Bt^T + bias computed as usual; output written as Vt[b][col][s] (bf16).
__global__ __launch_bounds__(256)
void gemm16_vt(const int* __restrict__ flg, const u16* __restrict__ A,
               const u16* __restrict__ Bt, const void* __restrict__ bias,
               u16* __restrict__ Vt, int M, int N, int K, int SB)
{
  __shared__ u16 As[BM * BK];
  __shared__ u16 Bs[BN * BK];
  __shared__ u16 xp[4][64 * 34];   // per-wave 64(S) x 32(D) bounce, stride 34

  const int f_in = flg[0];
  const int tid = threadIdx.x, lane = tid & 63, wave = tid >> 6;
  const int wm = wave >> 1, wn = wave & 1;
  const int m0 = blockIdx.y * BM, n0 = blockIdx.x * BN;

  const int rr  = wave * 32 + (lane >> 2);
  const int cc8 = (lane & 3) * 8;
  const u16* ga0 = A + (long)(m0 + rr) * K + cc8;
  const u16* ga1 = ga0 + 16 * (long)K;
  const u16* gb0 = Bt + (long)(n0 + rr) * K + cc8;
  const u16* gb1 = gb0 + 16 * (long)K;
  u16* la0 = &As[(wave * 2    ) * 512];
  u16* la1 = &As[(wave * 2 + 1) * 512];
  u16* lb0 = &Bs[(wave * 2    ) * 512];
  u16* lb1 = &Bs[(wave * 2 + 1) * 512];

  f4v acc[4][4];
#pragma unroll
  for (int i = 0; i < 4; ++i)
#pragma unroll
    for (int j = 0; j < 4; ++j) acc[i][j] = (f4v){0.f, 0.f, 0.f, 0.f};

  const int fr = lane & 15, fk = (lane >> 4) * 8;
  const int aoff = (wm * 64 + fr) * BK + fk;
  const int boff = (wn * 64 + fr) * BK + fk;

  for (int kt = 0; kt < K; kt += BK) {
    glds16(ga0, la0); glds16(ga1, la1);
    glds16(gb0, lb0); glds16(gb1, lb1);
    ga0 += BK; ga1 += BK; gb0 += BK; gb1 += BK;
    __syncthreads();

    s8v af[4], bfr[4];
#pragma unroll
    for (int mi = 0; mi < 4; ++mi) af[mi]  = *(const s8v*)&As[aoff + mi * 16 * BK];
#pragma unroll
    for (int ni = 0; ni < 4; ++ni) bfr[ni] = *(const s8v*)&Bs[boff + ni * 16 * BK];
#pragma unroll
    for (int mi = 0; mi < 4; ++mi)
#pragma unroll
      for (int ni = 0; ni < 4; ++ni)
        acc[mi][ni] = __builtin_amdgcn_mfma_f32_16x16x32_bf16(af[mi], bfr[ni], acc[mi][ni], 0, 0, 0);
    __syncthreads();
  }

  // transposed epilogue: two 32-col halves through wave-private LDS
  const int cr = (lane >> 4) * 4, ccl = lane & 15;
  const int b  = m0 / SB;                       // batch (BM tiles never straddle)
  const int s0 = (m0 % SB) + wm * 64;           // S base of this wave's tile
  u16* xw = &xp[wave][0];
  const long bbase = (long)b * N * SB;
#pragma unroll
  for (int h = 0; h < 2; ++h) {
#pragma unroll
    for (int nl = 0; nl < 2; ++nl) {
      const int ni = h * 2 + nl;
      const int gcol = n0 + wn * 64 + ni * 16 + ccl;
      const float bv = (f_in != 0) ? ((const float*)bias)[gcol]
                                   : bf2f(((const u16*)bias)[gcol]);
#pragma unroll
      for (int mi = 0; mi < 4; ++mi)
#pragma unroll
        for (int r = 0; r < 4; ++r)
          xw[(mi * 16 + cr + r) * 34 + nl * 16 + ccl] = f2bf(acc[mi][ni][r] + bv);
    }
    __syncthreads();
#pragma unroll
    for (int c = 0; c < 32; ++c) {
      const int gcol = n0 + wn * 64 + h * 32 + c;
      Vt[bbase + (long)gcol * SB + s0 + lane] = xw[lane * 34 + c];
    }
    __syncthreads();
  }
}

// ---------------- Q & K projections (one z=2 dispatch), static 3-MFMA split ----------------
__global__ __launch_bounds__(256)
void gemm_proj_qk(const int* __restrict__ flg,
                  const u16* __restrict__ Ah0, const u16* __restrict__ Al0,
                  const u16* __restrict__ Bh0, const u16* __restrict__ Bl0,
                  const void* __restrict__ bias0,
                  u16* __restrict__ oH0, u16* __restrict__ oL0,
                  const u16* __restrict__ Ah1, const u16* __restrict__ Al1,
                  const u16* __restrict__ Bh1, const u16* __restrict__ Bl1,
                  const void* __restrict__ bias1,
                  u16* __restrict__ oH1, u16* __restrict__ oL1,
                  int M, int N, int K)
{
  __shared__ u16 AsH[BM * BK];
  __shared__ u16 AsL[BM * BK];
  __shared__ u16 BsH[BN * BK];
  __shared__ u16 BsL[BN * BK];

  const int zb = blockIdx.z;
  const u16* Ah = zb ? Ah1 : Ah0;  const u16* Al = zb ? Al1 : Al0;
  const u16* Bh = zb ? Bh1 : Bh0;  const u16* Bl = zb ? Bl1 : Bl0;
  const void* bias = zb ? bias1 : bias0;
  u16* outH = zb ? oH1 : oH0;      u16* outL = zb ? oL1 : oL0;

  const int f_in = flg[0];
  const int tid = threadIdx.x, lane = tid & 63, wave = tid >> 6;
  const int wm = wave >> 1, wn = wave & 1;
  const int m0 = blockIdx.y * BM, n0 = blockIdx.x * BN;

  const int rr  = wave * 32 + (lane >> 2);
  const int cc8 = (lane & 3) * 8;
  const long ofsA0 = (long)(m0 + rr) * K + cc8;
  const long ofsB0 = (long)(n0 + rr) * K + cc8;
  const u16* gah0 = Ah + ofsA0;  const u16* gah1 = gah0 + 16 * (long)K;
  const u16* gal0 = Al + ofsA0;  const u16* gal1 = gal0 + 16 * (long)K;
  const u16* gbh0 = Bh + ofsB0;  const u16* gbh1 = gbh0 + 16 * (long)K;
  const u16* gbl0 = Bl + ofsB0;  const u16* gbl1 = gbl0 + 16 * (long)K;
  u16* lah0 = &AsH[(wave * 2) * 512];  u16* lah1 = lah0 + 512;
  u16* lal0 = &AsL[(wave * 2) * 512];  u16* lal1 = lal0 + 512;
  u16* lbh0 = &BsH[(wave * 2) * 512];  u16* lbh1 = lbh0 + 512;
  u16* lbl0 = &BsL[(wave * 2) * 512];  u16* lbl1 = lbl0 + 512;

  f4v acc[4][4];
#pragma unroll
  for (int i = 0; i < 4; ++i)
#pragma unroll
    for (int j = 0; j < 4; ++j) acc[i][j] = (f4v){0.f, 0.f, 0.f, 0.f};

  const int fr = lane & 15, fk = (lane >> 4) * 8;
  const int aoff = (wm * 64 + fr) * BK + fk;
  const int boff = (wn * 64 + fr) * BK + fk;

  for (int kt = 0; kt < K; kt += BK) {
    glds16(gah0, lah0); glds16(gah1, lah1);
    glds16(gal0, lal0); glds16(gal1, lal1);
    glds16(gbh0, lbh0); glds16(gbh1, lbh1);
    glds16(gbl0, lbl0); glds16(gbl1, lbl1);
    gah0 += BK; gah1 += BK; gal0 += BK; gal1 += BK;
    gbh0 += BK; gbh1 += BK; gbl0 += BK; gbl1 += BK;
    __syncthreads();

    s8v ah[4], al[4], bh[4], bl[4];
#pragma unroll
    for (int mi = 0; mi < 4; ++mi) {
      ah[mi] = *(const s8v*)&AsH[aoff + mi * 16 * BK];
      al[mi] = *(const s8v*)&AsL[aoff + mi * 16 * BK];
    }
#pragma unroll
    for (int ni = 0; ni < 4; ++ni) {
      bh[ni] = *(const s8v*)&BsH[boff + ni * 16 * BK];
      bl[ni] = *(const s8v*)&BsL[boff + ni * 16 * BK];
    }
#pragma unroll
    for (int mi = 0; mi < 4; ++mi)
#pragma unroll
      for (int ni = 0; ni < 4; ++ni) {
        acc[mi][ni] = __builtin_amdgcn_mfma_f32_16x16x32_bf16(ah[mi], bh[ni], acc[mi][ni], 0, 0, 0);
        acc[mi][ni] = __builtin_amdgcn_mfma_f32_16x16x32_bf16(ah[mi], bl[ni], acc[mi][ni], 0, 0, 0);
        acc[mi][ni] = __builtin_amdgcn_mfma_f32_16x16x32_bf16(al[mi], bh[ni], acc[mi][ni], 0, 0, 0);
      }
    __syncthreads();
  }

  const int cr = (lane >> 4) * 4, ccl = lane & 15;
#pragma unroll
  for (int ni = 0; ni < 4; ++ni) {
    const int gcol = n0 + wn * 64 + ni * 16 + ccl;
    const float bv = (f_in != 0) ? ((const float*)bias)[gcol]
                                 : bf2f(((const u16*)bias)[gcol]);
#pragma unroll
    for (int mi = 0; mi < 4; ++mi)
#pragma unroll
      for (int r = 0; r < 4; ++r) {
        const long grow = (long)(m0 + wm * 64 + mi * 16 + cr + r);
        const float val = acc[mi][ni][r] + bv;
        const long idx = grow * N + gcol;
        const u16 h = f2bf(val);
        outH[idx] = h;
        outL[idx] = f2bf(val - bf2f(h));
      }
  }
}

// ---------------- scores GEMM: 3-MFMA split, fp32 out ----------------
__global__ __launch_bounds__(256)
void gemm16s3(const u16* __restrict__ Ah, const u16* __restrict__ Al,
              const u16* __restrict__ Bh, const u16* __restrict__ Bl,
              float* __restrict__ C, int M, int N, int K,
              long sA, long sB, long sC)
{
  __shared__ u16 AsH[BM * BK];
  __shared__ u16 AsL[BM * BK];
  __shared__ u16 BsH[BN * BK];
  __shared__ u16 BsL[BN * BK];

  const int tid = threadIdx.x, lane = tid & 63, wave = tid >> 6;
  const int wm = wave >> 1, wn = wave & 1;
  const int m0 = blockIdx.y * BM, n0 = blockIdx.x * BN;
  const long z = blockIdx.z;

  const int rr  = wave * 32 + (lane >> 2);
  const int cc8 = (lane & 3) * 8;
  const long ofsA0 = (long)(m0 + rr) * K + cc8 + z * sA;
  const long ofsB0 = (long)(n0 + rr) * K + cc8 + z * sB;
  const u16* gah0 = Ah + ofsA0;  const u16* gah1 = gah0 + 16 * (long)K;
  const u16* gal0 = Al + ofsA0;  const u16* gal1 = gal0 + 16 * (long)K;
  const u16* gbh0 = Bh + ofsB0;  const u16* gbh1 = gbh0 + 16 * (long)K;
  const u16* gbl0 = Bl + ofsB0;  const u16* gbl1 = gbl0 + 16 * (long)K;
  u16* lah0 = &AsH[(wave * 2) * 512];  u16* lah1 = lah0 + 512;
  u16* lal0 = &AsL[(wave * 2) * 512];  u16* lal1 = lal0 + 512;
  u16* lbh0 = &BsH[(wave * 2) * 512];  u16* lbh1 = lbh0 + 512;
  u16* lbl0 = &BsL[(wave * 2) * 512];  u16* lbl1 = lbl0 + 512;

  f4v acc[4][4];
#pragma unroll
  for (int i = 0; i < 4; ++i)
#pragma unroll
    for (int j = 0; j < 4; ++j) acc[i][j] = (f4v){0.f, 0.f, 0.f, 0.f};

  const int fr = lane & 15, fk = (lane >> 4) * 8;
  const int aoff = (wm * 64 + fr) * BK + fk;
  const int boff = (wn * 64 + fr) * BK + fk;

  for (int kt = 0; kt < K; kt += BK) {
    glds16(gah0, lah0); glds16(gah1, lah1);
    glds16(gal0, lal0); glds16(gal1, lal1);
    glds16(gbh0, lbh0); glds16(gbh1, lbh1);
    glds16(gbl0, lbl0); glds16(gbl1, lbl1);
    gah0 += BK; gah1 += BK; gal0 += BK; gal1 += BK;
    gbh0 += BK; gbh1 += BK; gbl0 += BK; gbl1 += BK;
    __syncthreads();

    s8v ah[4], al[4], bh[4], bl[4];
#pragma unroll
    for (int mi = 0; mi < 4; ++mi) {
      ah[mi] = *(const s8v*)&AsH[aoff + mi * 16 * BK];
      al[mi] = *(const s8v*)&AsL[aoff + mi * 16 * BK];
    }
#pragma unroll
    for (int ni = 0; ni < 4; ++ni) {
      bh[ni] = *(const s8v*)&BsH[boff + ni * 16 * BK];
      bl[ni] = *(const s8v*)&BsL[boff + ni * 16 * BK];
    }
#pragma unroll
    for (int mi = 0; mi < 4; ++mi)
#pragma unroll
      for (int ni = 0; ni < 4; ++ni) {
        acc[mi][ni] = __builtin_amdgcn_mfma_f32_16x16x32_bf16(ah[mi], bh[ni], acc[mi][ni], 0, 0, 0);
        acc[mi][ni] = __builtin_amdgcn_mfma_f32_16x16x32_bf16(ah[mi], bl[ni], acc[mi][ni], 0, 0, 0);
        acc[mi][ni] = __builtin_amdgcn_mfma_f32_16x16x32_bf16(al[mi], bh[ni], acc[mi][ni], 0, 0, 0);
      }
    __syncthreads();
  }

  const int cr = (lane >> 4) * 4, ccl = lane & 15;
#pragma unroll
  for (int ni = 0; ni < 4; ++ni) {
    const int gcol = n0 + wn * 64 + ni * 16 + ccl;
#pragma unroll
    for (int mi = 0; mi < 4; ++mi)
#pragma unroll
      for (int r = 0; r < 4; ++r) {
        const long grow = (long)(m0 + wm * 64 + mi * 16 + cr + r);
        C[z * sC + grow * N + gcol] = acc[mi][ni][r];
      }
  }
}

// ---------------- row softmax fp32 -> bf16 attn, N=2048, one block/row ----------------
__global__ __launch_bounds__(256)
void softmax_rows_bf(const float* __restrict__ S, u16* __restrict__ P, int N)
{
  const float* row = S + (long)blockIdx.x * N;
  u16* prow = P + (long)blockIdx.x * N;
  const int t = threadIdx.x;
  f4v v0 = *(const f4v*)(row + t * 8);
  f4v v1 = *(const f4v*)(row + t * 8 + 4);

  float m = v0[0];
#pragma unroll
  for (int j = 1; j < 4; ++j) m = fmaxf(m, v0[j]);
#pragma unroll
  for (int j = 0; j < 4; ++j) m = fmaxf(m, v1[j]);
  for (int off = 32; off > 0; off >>= 1) m = fmaxf(m, __shfl_down(m, off, 64));

  __shared__ float redm[4], reds[4];
  if ((t & 63) == 0) redm[t >> 6] = m;
  __syncthreads();
  m = fmaxf(fmaxf(redm[0], redm[1]), fmaxf(redm[2], redm[3]));

  float s = 0.f;
#pragma unroll
  for (int j = 0; j < 4; ++j) { v0[j] = __expf(v0[j] - m); s += v0[j]; }
#pragma unroll
  for (int j = 0; j < 4; ++j) { v1[j] = __expf(v1[j] - m); s += v1[j]; }
  for (int off = 32; off > 0; off >>= 1) s += __shfl_down(s, off, 64);
  if ((t & 63) == 0) reds[t >> 6] = s;
  __syncthreads();
  s = reds[0] + reds[1] + reds[2] + reds[3];

  const float inv = 1.f / s;
  s8v o;
#pragma unroll
  for (int j = 0; j < 4; ++j) {
    o[j]     = (short)f2bf(v0[j] * inv);
    o[4 + j] = (short)f2bf(v1[j] * inv);
  }
  *(s8v*)(prow + t * 8) = o;
}

extern "C" void kernel_launch(void* const* d_in, const int* in_sizes, int n_in,
                              void* d_out, int out_size, void* d_ws, size_t ws_size,
                              hipStream_t stream)
{
  const void* query = d_in[0];
  const void* kv    = d_in[1];
  const void* Wq    = d_in[2];
  const void* bq    = d_in[3];
  const void* Wk    = d_in[4];
  const void* bk    = d_in[5];
  const void* Wv    = d_in[6];
  const void* bv    = d_in[7];
  const void* Wo    = d_in[8];
  const void* bo    = d_in[9];

  const int Bn = 4, S = 2048, D = 1024;
  const int MS = Bn * S;                       // 8192
  const size_t KBu = 1024, MBu = 1024 * 1024;
  const long nTok = (long)MS * D;              // 8388608 elems

  // ---- workspace layout (total ~172.1 MB) ----
  char* ws = (char*)d_ws;
  int*   flg  = (int*)(ws);
  char*  rA   = ws + 64 * KBu;                 // 64MB: input planes, later Sc
  u16*   Qih  = (u16*)(rA);
  u16*   Qil  = (u16*)(rA + 16 * MBu);
  u16*   KVh  = (u16*)(rA + 32 * MBu);
  u16*   KVl  = (u16*)(rA + 48 * MBu);
  float* Sc   = (float*)(rA);                  // 64MB fp32 scores (inputs dead by then)
  char*  rW   = rA + 64 * MBu;                 // 12MB: W^T planes
  u16*   WqTh = (u16*)(rW);
  u16*   WqTl = (u16*)(rW + 2 * MBu);
  u16*   WkTh = (u16*)(rW + 4 * MBu);
  u16*   WkTl = (u16*)(rW + 6 * MBu);
  u16*   WvTh = (u16*)(rW + 8 * MBu);
  u16*   WoTh = (u16*)(rW + 10 * MBu);
  char*  rQK  = rW + 12 * MBu;                 // 64MB: Q/K planes, later attn
  u16*   Qh   = (u16*)(rQK);
  u16*   Ql   = (u16*)(rQK + 16 * MBu);
  u16*   Kh   = (u16*)(rQK + 32 * MBu);
  u16*   Kl   = (u16*)(rQK + 48 * MBu);
  u16*   attn = (u16*)(rQK);                   // 32MB bf16 (Q planes dead after scores)
  char*  rV   = rQK + 64 * MBu;                // 32MB
  u16*   Vt   = (u16*)(rV);                    // [B][D][S] bf16, written directly by V-proj
  u16*   Cx   = (u16*)(rV + 16 * MBu);         // ctx [B][S][D] bf16

  detect_dtype<<<1, 256, 0, stream>>>((const u16*)query, flg);

  convert_hl2<<<dim3((unsigned)(nTok / 2048), 2), 256, 0, stream>>>(
      flg, query, kv, Qih, Qil, KVh, KVl, nTok);

  dim3 tb(32, 8);
  transpose_w4<<<dim3(32, 32, 4), tb, 0, stream>>>(
      flg, Wq, Wk, Wv, Wo, WqTh, WkTh, WvTh, WoTh, WqTl, WkTl, D);

  // Q & K projections (split 3x) in one dispatch; V projection writes Vt directly
  gemm_proj_qk<<<dim3(D / BN, MS / BM, 2), 256, 0, stream>>>(
      flg, Qih, Qil, WqTh, WqTl, bq, Qh, Ql,
           KVh, KVl, WkTh, WkTl, bk, Kh, Kl, MS, D, D);
  gemm16_vt<<<dim3(D / BN, MS / BM, 1), 256, 0, stream>>>(
      flg, KVh, WvTh, bv, Vt, MS, D, D, S);

  // scores (split 3x, fp32), softmax -> bf16 attn, PV (plain bf16)
  gemm16s3<<<dim3(S / BN, S / BM, Bn), 256, 0, stream>>>(
      Qh, Ql, Kh, Kl, Sc, S, S, D, (long)S * D, (long)S * D, (long)S * S);
  softmax_rows_bf<<<dim3(Bn * S), 256, 0, stream>>>(Sc, attn, S);
  gemm16<false, false><<<dim3(D / BN, S / BM, Bn), 256, 0, stream>>>(
      flg, attn, Vt, nullptr, Cx, S, D, S, (long)S * S, (long)D * S, (long)S * D);

  // output projection -> d_out (dtype per flag)
  gemm16<true, true><<<dim3(D / BN, MS / BM, 1), 256, 0, stream>>>(
      flg, Cx, WoTh, bo, d_out, MS, D, D, 0L, 0L, 0L);
}

// Round 7
// 416.976 us; speedup vs baseline: 2.3568x; 1.2943x over previous
//
#include <hip/hip_runtime.h>
#include <cstdint>

typedef unsigned short u16;
typedef _Float16 f16;
typedef __attribute__((ext_vector_type(8))) short    s8v;  // 8 bf16 (4 VGPRs)
typedef __attribute__((ext_vector_type(8))) _Float16 h8v;  // 8 fp16 (4 VGPRs)
typedef __attribute__((ext_vector_type(4))) float    f4v;

__device__ __forceinline__ float bf2f(u16 b) {
  unsigned int u = ((unsigned int)b) << 16;
  float f;
  __builtin_memcpy(&f, &u, 4);
  return f;
}
__device__ __forceinline__ u16 f2bf(float f) {
  unsigned int u;
  __builtin_memcpy(&u, &f, 4);
  u += 0x7fffu + ((u >> 16) & 1u);   // RNE (finite inputs only)
  return (u16)(u >> 16);
}

// async global->LDS, 16B per lane; LDS dest = wave-uniform base + lane*16
__device__ __forceinline__ void glds16(const void* g, void* l) {
  __builtin_amdgcn_global_load_lds(
      (const __attribute__((address_space(1))) unsigned int*)g,
      (__attribute__((address_space(3))) unsigned int*)l, 16, 0, 0);
}

#define BM 128
#define BN 128
#define BK 32

// ---------------- dtype detector (flg[0]=1: fp32 storage, 0: bf16) ----------------
__global__ __launch_bounds__(256)
void detect_dtype(const u16* __restrict__ q, int* __restrict__ flg)
{
  __shared__ int cbig, czero;
  if (threadIdx.x == 0) { cbig = 0; czero = 0; }
  __syncthreads();
  int b = 0, z = 0;
  for (int i = threadIdx.x; i < 4096; i += 256) {
    float v = bf2f(q[i]);
    if (!(fabsf(v) < 1e4f)) b++;
    if ((i & 1) == 0 && q[i] == 0) z++;
  }
  atomicAdd(&cbig, b);
  atomicAdd(&czero, z);
  __syncthreads();
  if (threadIdx.x == 0) flg[0] = (cbig > 64 || czero > 1600) ? 1 : 0;
}

// ---------------- inputs -> fp16 plane (query & kv in one launch) ----------------
__global__ __launch_bounds__(256)
void convert_h(const int* __restrict__ flg,
               const void* __restrict__ q, const void* __restrict__ kv,
               f16* __restrict__ qo, f16* __restrict__ kvo, long n)
{
  const void* in = blockIdx.y ? kv : q;
  f16* out = blockIdx.y ? kvo : qo;
  const long i = ((long)blockIdx.x * 256 + threadIdx.x) * 8;
  if (i >= n) return;
  h8v h;
  if (flg[0] != 0) {
    const float* p = (const float*)in + i;
    f4v f0 = *(const f4v*)p;
    f4v f1 = *(const f4v*)(p + 4);
#pragma unroll
    for (int j = 0; j < 4; ++j) {
      h[j]     = (f16)f0[j];
      h[4 + j] = (f16)f1[j];
    }
  } else {
    s8v b = *(const s8v*)((const short*)in + i);
#pragma unroll
    for (int j = 0; j < 8; ++j) h[j] = (f16)bf2f((u16)b[j]);
  }
  *(h8v*)(out + i) = h;
}

// ---------------- four W^T in one launch: z<3 -> fp16 (Wq,Wk,Wv); z=3 -> bf16 (Wo) ----
__global__ __launch_bounds__(256)
void transpose_w4(const int* __restrict__ flg,
                  const void* __restrict__ w0, const void* __restrict__ w1,
                  const void* __restrict__ w2, const void* __restrict__ w3,
                  f16* __restrict__ h0, f16* __restrict__ h1,
                  f16* __restrict__ h2, u16* __restrict__ b3, int D)
{
  __shared__ float tile[32][33];
  const int zb = blockIdx.z;
  const void* in_v = (zb == 0) ? w0 : (zb == 1) ? w1 : (zb == 2) ? w2 : w3;
  const bool i32 = (flg[0] != 0);
  const u16*   in16 = (const u16*)in_v;
  const float* in32 = (const float*)in_v;
  const int c0 = blockIdx.x * 32, r0 = blockIdx.y * 32;
  const int tx = threadIdx.x, ty = threadIdx.y;   // block (32,8)
  for (int i = ty; i < 32; i += 8) {
    const long idx = (long)(r0 + i) * D + c0 + tx;
    tile[i][tx] = i32 ? in32[idx] : bf2f(in16[idx]);
  }
  __syncthreads();
  f16* outH = (zb == 0) ? h0 : (zb == 1) ? h1 : h2;
  for (int i = ty; i < 32; i += 8) {
    const long idx = (long)(c0 + i) * D + r0 + tx;
    const float v = tile[tx][i];
    if (zb == 3) b3[idx]   = f2bf(v);
    else         outH[idx] = (f16)v;
  }
}

// ---------------- fp16 NT GEMM core macro-parts (m97 structure) ----------------
// Q & K projections in one z=2 dispatch: fp16 A,B; fp16 out plane.
__global__ __launch_bounds__(256)
void gemm_proj_qk(const int* __restrict__ flg,
                  const f16* __restrict__ A0, const f16* __restrict__ B0,
                  const void* __restrict__ bias0, f16* __restrict__ o0,
                  const f16* __restrict__ A1, const f16* __restrict__ B1,
                  const void* __restrict__ bias1, f16* __restrict__ o1,
                  int M, int N, int K)
{
  __shared__ u16 As[BM * BK];
  __shared__ u16 Bs[BN * BK];

  const int zb = blockIdx.z;
  const f16* A = zb ? A1 : A0;
  const f16* B = zb ? B1 : B0;
  const void* bias = zb ? bias1 : bias0;
  f16* out = zb ? o1 : o0;

  const int f_in = flg[0];
  const int tid = threadIdx.x, lane = tid & 63, wave = tid >> 6;
  const int wm = wave >> 1, wn = wave & 1;
  const int m0 = blockIdx.y * BM, n0 = blockIdx.x * BN;

  const int rr  = wave * 32 + (lane >> 2);
  const int cc8 = (lane & 3) * 8;
  const f16* ga0 = A + (long)(m0 + rr) * K + cc8;
  const f16* ga1 = ga0 + 16 * (long)K;
  const f16* gb0 = B + (long)(n0 + rr) * K + cc8;
  const f16* gb1 = gb0 + 16 * (long)K;
  u16* la0 = &As[(wave * 2    ) * 512];
  u16* la1 = &As[(wave * 2 + 1) * 512];
  u16* lb0 = &Bs[(wave * 2    ) * 512];
  u16* lb1 = &Bs[(wave * 2 + 1) * 512];

  f4v acc[4][4];
#pragma unroll
  for (int i = 0; i < 4; ++i)
#pragma unroll
    for (int j = 0; j < 4; ++j) acc[i][j] = (f4v){0.f, 0.f, 0.f, 0.f};

  const int fr = lane & 15, fk = (lane >> 4) * 8;
  const int aoff = (wm * 64 + fr) * BK + fk;
  const int boff = (wn * 64 + fr) * BK + fk;

  for (int kt = 0; kt < K; kt += BK) {
    glds16(ga0, la0); glds16(ga1, la1);
    glds16(gb0, lb0); glds16(gb1, lb1);
    ga0 += BK; ga1 += BK; gb0 += BK; gb1 += BK;
    __syncthreads();

    h8v af[4], bfr[4];
#pragma unroll
    for (int mi = 0; mi < 4; ++mi) af[mi]  = *(const h8v*)&As[aoff + mi * 16 * BK];
#pragma unroll
    for (int ni = 0; ni < 4; ++ni) bfr[ni] = *(const h8v*)&Bs[boff + ni * 16 * BK];
#pragma unroll
    for (int mi = 0; mi < 4; ++mi)
#pragma unroll
      for (int ni = 0; ni < 4; ++ni)
        acc[mi][ni] = __builtin_amdgcn_mfma_f32_16x16x32_f16(af[mi], bfr[ni], acc[mi][ni], 0, 0, 0);
    __syncthreads();
  }

  const int cr = (lane >> 4) * 4, ccl = lane & 15;
#pragma unroll
  for (int ni = 0; ni < 4; ++ni) {
    const int gcol = n0 + wn * 64 + ni * 16 + ccl;
    const float bv = (f_in != 0) ? ((const float*)bias)[gcol]
                                 : bf2f(((const u16*)bias)[gcol]);
#pragma unroll
    for (int mi = 0; mi < 4; ++mi)
#pragma unroll
      for (int r = 0; r < 4; ++r) {
        const long grow = (long)(m0 + wm * 64 + mi * 16 + cr + r);
        out[grow * N + gcol] = (f16)(acc[mi][ni][r] + bv);
      }
  }
}

// ---------------- V-projection (fp16 in) with fused transposed bf16 epilogue ----------------
__global__ __launch_bounds__(256)
void gemm_vt(const int* __restrict__ flg, const f16* __restrict__ A,
             const f16* __restrict__ B, const void* __restrict__ bias,
             u16* __restrict__ Vt, int M, int N, int K, int SB)
{
  __shared__ u16 As[BM * BK];
  __shared__ u16 Bs[BN * BK];
  __shared__ u16 xp[4][64 * 34];

  const int f_in = flg[0];
  const int tid = threadIdx.x, lane = tid & 63, wave = tid >> 6;
  const int wm = wave >> 1, wn = wave & 1;
  const int m0 = blockIdx.y * BM, n0 = blockIdx.x * BN;

  const int rr  = wave * 32 + (lane >> 2);
  const int cc8 = (lane & 3) * 8;
  const f16* ga0 = A + (long)(m0 + rr) * K + cc8;
  const f16* ga1 = ga0 + 16 * (long)K;
  const f16* gb0 = B + (long)(n0 + rr) * K + cc8;
  const f16* gb1 = gb0 + 16 * (long)K;
  u16* la0 = &As[(wave * 2    ) * 512];
  u16* la1 = &As[(wave * 2 + 1) * 512];
  u16* lb0 = &Bs[(wave * 2    ) * 512];
  u16* lb1 = &Bs[(wave * 2 + 1) * 512];

  f4v acc[4][4];
#pragma unroll
  for (int i = 0; i < 4; ++i)
#pragma unroll
    for (int j = 0; j < 4; ++j) acc[i][j] = (f4v){0.f, 0.f, 0.f, 0.f};

  const int fr = lane & 15, fk = (lane >> 4) * 8;
  const int aoff = (wm * 64 + fr) * BK + fk;
  const int boff = (wn * 64 + fr) * BK + fk;

  for (int kt = 0; kt < K; kt += BK) {
    glds16(ga0, la0); glds16(ga1, la1);
    glds16(gb0, lb0); glds16(gb1, lb1);
    ga0 += BK; ga1 += BK; gb0 += BK; gb1 += BK;
    __syncthreads();

    h8v af[4], bfr[4];
#pragma unroll
    for (int mi = 0; mi < 4; ++mi) af[mi]  = *(const h8v*)&As[aoff + mi * 16 * BK];
#pragma unroll
    for (int ni = 0; ni < 4; ++ni) bfr[ni] = *(const h8v*)&Bs[boff + ni * 16 * BK];
#pragma unroll
    for (int mi = 0; mi < 4; ++mi)
#pragma unroll
      for (int ni = 0; ni < 4; ++ni)
        acc[mi][ni] = __builtin_amdgcn_mfma_f32_16x16x32_f16(af[mi], bfr[ni], acc[mi][ni], 0, 0, 0);
    __syncthreads();
  }

  // transposed epilogue: two 32-col halves through wave-private LDS
  const int cr = (lane >> 4) * 4, ccl = lane & 15;
  const int b  = m0 / SB;
  const int s0 = (m0 % SB) + wm * 64;
  u16* xw = &xp[wave][0];
  const long bbase = (long)b * N * SB;
#pragma unroll
  for (int h = 0; h < 2; ++h) {
#pragma unroll
    for (int nl = 0; nl < 2; ++nl) {
      const int ni = h * 2 + nl;
      const int gcol = n0 + wn * 64 + ni * 16 + ccl;
      const float bv = (f_in != 0) ? ((const float*)bias)[gcol]
                                   : bf2f(((const u16*)bias)[gcol]);
#pragma unroll
      for (int mi = 0; mi < 4; ++mi)
#pragma unroll
        for (int r = 0; r < 4; ++r)
          xw[(mi * 16 + cr + r) * 34 + nl * 16 + ccl] = f2bf(acc[mi][ni][r] + bv);
    }
    __syncthreads();
#pragma unroll
    for (int c = 0; c < 32; ++c) {
      const int gcol = n0 + wn * 64 + h * 32 + c;
      Vt[bbase + (long)gcol * SB + s0 + lane] = xw[lane * 34 + c];
    }
    __syncthreads();
  }
}

// ---------------- scores GEMM: fp16 1x, fp32 out ----------------
__global__ __launch_bounds__(256)
void gemm_sc(const f16* __restrict__ A, const f16* __restrict__ B,
             float* __restrict__ C, int M, int N, int K,
             long sA, long sB, long sC)
{
  __shared__ u16 As[BM * BK];
  __shared__ u16 Bs[BN * BK];

  const int tid = threadIdx.x, lane = tid & 63, wave = tid >> 6;
  const int wm = wave >> 1, wn = wave & 1;
  const int m0 = blockIdx.y * BM, n0 = blockIdx.x * BN;
  const long z = blockIdx.z;

  const int rr  = wave * 32 + (lane >> 2);
  const int cc8 = (lane & 3) * 8;
  const f16* ga0 = A + (long)(m0 + rr) * K + cc8 + z * sA;
  const f16* ga1 = ga0 + 16 * (long)K;
  const f16* gb0 = B + (long)(n0 + rr) * K + cc8 + z * sB;
  const f16* gb1 = gb0 + 16 * (long)K;
  u16* la0 = &As[(wave * 2    ) * 512];
  u16* la1 = &As[(wave * 2 + 1) * 512];
  u16* lb0 = &Bs[(wave * 2    ) * 512];
  u16* lb1 = &Bs[(wave * 2 + 1) * 512];

  f4v acc[4][4];
#pragma unroll
  for (int i = 0; i < 4; ++i)
#pragma unroll
    for (int j = 0; j < 4; ++j) acc[i][j] = (f4v){0.f, 0.f, 0.f, 0.f};

  const int fr = lane & 15, fk = (lane >> 4) * 8;
  const int aoff = (wm * 64 + fr) * BK + fk;
  const int boff = (wn * 64 + fr) * BK + fk;

  for (int kt = 0; kt < K; kt += BK) {
    glds16(ga0, la0); glds16(ga1, la1);
    glds16(gb0, lb0); glds16(gb1, lb1);
    ga0 += BK; ga1 += BK; gb0 += BK; gb1 += BK;
    __syncthreads();

    h8v af[4], bfr[4];
#pragma unroll
    for (int mi = 0; mi < 4; ++mi) af[mi]  = *(const h8v*)&As[aoff + mi * 16 * BK];
#pragma unroll
    for (int ni = 0; ni < 4; ++ni) bfr[ni] = *(const h8v*)&Bs[boff + ni * 16 * BK];
#pragma unroll
    for (int mi = 0; mi < 4; ++mi)
#pragma unroll
      for (int ni = 0; ni < 4; ++ni)
        acc[mi][ni] = __builtin_amdgcn_mfma_f32_16x16x32_f16(af[mi], bfr[ni], acc[mi][ni], 0, 0, 0);
    __syncthreads();
  }

  const int cr = (lane >> 4) * 4, ccl = lane & 15;
#pragma unroll
  for (int ni = 0; ni < 4; ++ni) {
    const int gcol = n0 + wn * 64 + ni * 16 + ccl;
#pragma unroll
    for (int mi = 0; mi < 4; ++mi)
#pragma unroll
      for (int r = 0; r < 4; ++r) {
        const long grow = (long)(m0 + wm * 64 + mi * 16 + cr + r);
        C[z * sC + grow * N + gcol] = acc[mi][ni][r];
      }
  }
}

// ---------------- plain bf16 NT GEMM (PV, out-proj) ----------------
template<bool OUT_FLAG, bool HAS_BIAS>
__global__ __launch_bounds__(256)
void gemm16(const int* __restrict__ flg, const u16* __restrict__ A,
            const u16* __restrict__ Bt, const void* __restrict__ bias,
            void* __restrict__ Cv, int M, int N, int K,
            long sA, long sB, long sC)
{
  __shared__ u16 As[BM * BK];
  __shared__ u16 Bs[BN * BK];

  const int f_in = flg[0];
  const int tid = threadIdx.x, lane = tid & 63, wave = tid >> 6;
  const int wm = wave >> 1, wn = wave & 1;
  const int m0 = blockIdx.y * BM, n0 = blockIdx.x * BN;
  const long z = blockIdx.z;
  const u16* Ap = A + z * sA;
  const u16* Bp = Bt + z * sB;

  const int rr  = wave * 32 + (lane >> 2);
  const int cc8 = (lane & 3) * 8;
  const u16* ga0 = Ap + (long)(m0 + rr) * K + cc8;
  const u16* ga1 = ga0 + 16 * (long)K;
  const u16* gb0 = Bp + (long)(n0 + rr) * K + cc8;
  const u16* gb1 = gb0 + 16 * (long)K;
  u16* la0 = &As[(wave * 2    ) * 512];
  u16* la1 = &As[(wave * 2 + 1) * 512];
  u16* lb0 = &Bs[(wave * 2    ) * 512];
  u16* lb1 = &Bs[(wave * 2 + 1) * 512];

  f4v acc[4][4];
#pragma unroll
  for (int i = 0; i < 4; ++i)
#pragma unroll
    for (int j = 0; j < 4; ++j) acc[i][j] = (f4v){0.f, 0.f, 0.f, 0.f};

  const int fr = lane & 15, fk = (lane >> 4) * 8;
  const int aoff = (wm * 64 + fr) * BK + fk;
  const int boff = (wn * 64 + fr) * BK + fk;

  for (int kt = 0; kt < K; kt += BK) {
    glds16(ga0, la0); glds16(ga1, la1);
    glds16(gb0, lb0); glds16(gb1, lb1);
    ga0 += BK; ga1 += BK; gb0 += BK; gb1 += BK;
    __syncthreads();

    s8v af[4], bfr[4];
#pragma unroll
    for (int mi = 0; mi < 4; ++mi) af[mi]  = *(const s8v*)&As[aoff + mi * 16 * BK];
#pragma unroll
    for (int ni = 0; ni < 4; ++ni) bfr[ni] = *(const s8v*)&Bs[boff + ni * 16 * BK];
#pragma unroll
    for (int mi = 0; mi < 4; ++mi)
#pragma unroll
      for (int ni = 0; ni < 4; ++ni)
        acc[mi][ni] = __builtin_amdgcn_mfma_f32_16x16x32_bf16(af[mi], bfr[ni], acc[mi][ni], 0, 0, 0);
    __syncthreads();
  }

  const int cr = (lane >> 4) * 4, ccl = lane & 15;
  const bool o32 = OUT_FLAG && (f_in != 0);
#pragma unroll
  for (int ni = 0; ni < 4; ++ni) {
    const int gcol = n0 + wn * 64 + ni * 16 + ccl;
    float bv = 0.f;
    if (HAS_BIAS)
      bv = (f_in != 0) ? ((const float*)bias)[gcol] : bf2f(((const u16*)bias)[gcol]);
#pragma unroll
    for (int mi = 0; mi < 4; ++mi)
#pragma unroll
      for (int r = 0; r < 4; ++r) {
        const long grow = (long)(m0 + wm * 64 + mi * 16 + cr + r);
        const float val = acc[mi][ni][r] + bv;
        const long idx = z * sC + grow * N + gcol;
        if (o32) ((float*)Cv)[idx] = val;
        else     ((u16*)Cv)[idx]   = f2bf(val);
      }
  }
}

// ---------------- row softmax fp32 -> bf16 attn, N=2048, one block/row ----------------
__global__ __launch_bounds__(256)
void softmax_rows_bf(const float* __restrict__ S, u16* __restrict__ P, int N)
{
  const float* row = S + (long)blockIdx.x * N;
  u16* prow = P + (long)blockIdx.x * N;
  const int t = threadIdx.x;
  f4v v0 = *(const f4v*)(row + t * 8);
  f4v v1 = *(const f4v*)(row + t * 8 + 4);

  float m = v0[0];
#pragma unroll
  for (int j = 1; j < 4; ++j) m = fmaxf(m, v0[j]);
#pragma unroll
  for (int j = 0; j < 4; ++j) m = fmaxf(m, v1[j]);
  for (int off = 32; off > 0; off >>= 1) m = fmaxf(m, __shfl_down(m, off, 64));

  __shared__ float redm[4], reds[4];
  if ((t & 63) == 0) redm[t >> 6] = m;
  __syncthreads();
  m = fmaxf(fmaxf(redm[0], redm[1]), fmaxf(redm[2], redm[3]));

  float s = 0.f;
#pragma unroll
  for (int j = 0; j < 4; ++j) { v0[j] = __expf(v0[j] - m); s += v0[j]; }
#pragma unroll
  for (int j = 0; j < 4; ++j) { v1[j] = __expf(v1[j] - m); s += v1[j]; }
  for (int off = 32; off > 0; off >>= 1) s += __shfl_down(s, off, 64);
  if ((t & 63) == 0) reds[t >> 6] = s;
  __syncthreads();
  s = reds[0] + reds[1] + reds[2] + reds[3];

  const float inv = 1.f / s;
  s8v o;
#pragma unroll
  for (int j = 0; j < 4; ++j) {
    o[j]     = (short)f2bf(v0[j] * inv);
    o[4 + j] = (short)f2bf(v1[j] * inv);
  }
  *(s8v*)(prow + t * 8) = o;
}

extern "C" void kernel_launch(void* const* d_in, const int* in_sizes, int n_in,
                              void* d_out, int out_size, void* d_ws, size_t ws_size,
                              hipStream_t stream)
{
  const void* query = d_in[0];
  const void* kv    = d_in[1];
  const void* Wq    = d_in[2];
  const void* bq    = d_in[3];
  const void* Wk    = d_in[4];
  const void* bk    = d_in[5];
  const void* Wv    = d_in[6];
  const void* bv    = d_in[7];
  const void* Wo    = d_in[8];
  const void* bo    = d_in[9];

  const int Bn = 4, S = 2048, D = 1024;
  const int MS = Bn * S;                       // 8192
  const size_t KBu = 1024, MBu = 1024 * 1024;
  const long nTok = (long)MS * D;

  // ---- workspace layout (~168 MB; ws proven >= 173 MB) ----
  char* ws = (char*)d_ws;
  int*  flg  = (int*)(ws);
  f16*  Qi   = (f16*)(ws + 64 * KBu);          // 16MB fp16 input tokens
  f16*  KVi  = (f16*)(ws + 64 * KBu + 16 * MBu);
  char* rW   = ws + 64 * KBu + 32 * MBu;       // 8MB: W^T
  f16*  WqT  = (f16*)(rW);
  f16*  WkT  = (f16*)(rW + 2 * MBu);
  f16*  WvT  = (f16*)(rW + 4 * MBu);
  u16*  WoT  = (u16*)(rW + 6 * MBu);
  char* rQK  = rW + 8 * MBu;                   // 32MB: Q,K fp16; later attn bf16
  f16*  Qf   = (f16*)(rQK);
  f16*  Kf   = (f16*)(rQK + 16 * MBu);
  u16*  attn = (u16*)(rQK);                    // 32MB (Q/K dead after scores)
  float* Sc  = (float*)(rQK + 32 * MBu);       // 64MB fp32 scores
  char* rV   = rQK + 96 * MBu;                 // 32MB
  u16*  Vt   = (u16*)(rV);                     // [B][D][S] bf16
  u16*  Cx   = (u16*)(rV + 16 * MBu);          // [B][S][D] bf16

  detect_dtype<<<1, 256, 0, stream>>>((const u16*)query, flg);

  convert_h<<<dim3((unsigned)(nTok / 2048), 2), 256, 0, stream>>>(
      flg, query, kv, Qi, KVi, nTok);

  dim3 tb(32, 8);
  transpose_w4<<<dim3(32, 32, 4), tb, 0, stream>>>(
      flg, Wq, Wk, Wv, Wo, WqT, WkT, WvT, WoT, D);

  // Q & K projections (fp16 1x) in one dispatch; V projection writes Vt directly
  gemm_proj_qk<<<dim3(D / BN, MS / BM, 2), 256, 0, stream>>>(
      flg, Qi, WqT, bq, Qf, KVi, WkT, bk, Kf, MS, D, D);
  gemm_vt<<<dim3(D / BN, MS / BM, 1), 256, 0, stream>>>(
      flg, KVi, WvT, bv, Vt, MS, D, D, S);

  // scores (fp16 1x, fp32 out), softmax -> bf16 attn, PV (bf16)
  gemm_sc<<<dim3(S / BN, S / BM, Bn), 256, 0, stream>>>(
      Qf, Kf, Sc, S, S, D, (long)S * D, (long)S * D, (long)S * S);
  softmax_rows_bf<<<dim3(Bn * S), 256, 0, stream>>>(Sc, attn, S);
  gemm16<false, false><<<dim3(D / BN, S / BM, Bn), 256, 0, stream>>>(
      flg, attn, Vt, nullptr, Cx, S, D, S, (long)S * S, (long)D * S, (long)S * D);

  // output projection -> d_out (dtype per flag)
  gemm16<true, true><<<dim3(D / BN, MS / BM, 1), 256, 0, stream>>>(
      flg, Cx, WoT, bo, d_out, MS, D, D, 0L, 0L, 0L);
}

// Round 8
// 381.846 us; speedup vs baseline: 2.5737x; 1.0920x over previous
//
#include <hip/hip_runtime.h>
#include <cstdint>

typedef unsigned short u16;
typedef _Float16 f16;
typedef __attribute__((ext_vector_type(8))) short    s8v;  // 8 bf16 (4 VGPRs)
typedef __attribute__((ext_vector_type(8))) _Float16 h8v;  // 8 fp16 (4 VGPRs)
typedef __attribute__((ext_vector_type(4))) float    f4v;

__device__ __forceinline__ float bf2f(u16 b) {
  unsigned int u = ((unsigned int)b) << 16;
  float f;
  __builtin_memcpy(&f, &u, 4);
  return f;
}
__device__ __forceinline__ u16 f2bf(float f) {
  unsigned int u;
  __builtin_memcpy(&u, &f, 4);
  u += 0x7fffu + ((u >> 16) & 1u);   // RNE (finite inputs only)
  return (u16)(u >> 16);
}

// async global->LDS, 16B per lane; LDS dest = wave-uniform base + lane*16
__device__ __forceinline__ void glds16(const void* g, void* l) {
  __builtin_amdgcn_global_load_lds(
      (const __attribute__((address_space(1))) unsigned int*)g,
      (__attribute__((address_space(3))) unsigned int*)l, 16, 0, 0);
}

#define BM 128
#define BN 128
// BK=64 as two BK=32 subtiles (keeps the verified chunk->fragment layout).
// Per iter: 8 glds16/wave, 32 MFMA/wave -> 2x barrier amortization vs BK=32.

// ---------------- dtype detector (flg[0]=1: fp32 storage, 0: bf16) ----------------
__global__ __launch_bounds__(256)
void detect_dtype(const u16* __restrict__ q, int* __restrict__ flg)
{
  __shared__ int cbig, czero;
  if (threadIdx.x == 0) { cbig = 0; czero = 0; }
  __syncthreads();
  int b = 0, z = 0;
  for (int i = threadIdx.x; i < 4096; i += 256) {
    float v = bf2f(q[i]);
    if (!(fabsf(v) < 1e4f)) b++;
    if ((i & 1) == 0 && q[i] == 0) z++;
  }
  atomicAdd(&cbig, b);
  atomicAdd(&czero, z);
  __syncthreads();
  if (threadIdx.x == 0) flg[0] = (cbig > 64 || czero > 1600) ? 1 : 0;
}

// ---------------- inputs -> fp16 plane (query & kv in one launch) ----------------
__global__ __launch_bounds__(256)
void convert_h(const int* __restrict__ flg,
               const void* __restrict__ q, const void* __restrict__ kv,
               f16* __restrict__ qo, f16* __restrict__ kvo, long n)
{
  const void* in = blockIdx.y ? kv : q;
  f16* out = blockIdx.y ? kvo : qo;
  const long i = ((long)blockIdx.x * 256 + threadIdx.x) * 8;
  if (i >= n) return;
  h8v h;
  if (flg[0] != 0) {
    const float* p = (const float*)in + i;
    f4v f0 = *(const f4v*)p;
    f4v f1 = *(const f4v*)(p + 4);
#pragma unroll
    for (int j = 0; j < 4; ++j) {
      h[j]     = (f16)f0[j];
      h[4 + j] = (f16)f1[j];
    }
  } else {
    s8v b = *(const s8v*)((const short*)in + i);
#pragma unroll
    for (int j = 0; j < 8; ++j) h[j] = (f16)bf2f((u16)b[j]);
  }
  *(h8v*)(out + i) = h;
}

// ---------------- four W^T in one launch: z<3 -> fp16 (Wq,Wk,Wv); z=3 -> bf16 (Wo) ----
__global__ __launch_bounds__(256)
void transpose_w4(const int* __restrict__ flg,
                  const void* __restrict__ w0, const void* __restrict__ w1,
                  const void* __restrict__ w2, const void* __restrict__ w3,
                  f16* __restrict__ h0, f16* __restrict__ h1,
                  f16* __restrict__ h2, u16* __restrict__ b3, int D)
{
  __shared__ float tile[32][33];
  const int zb = blockIdx.z;
  const void* in_v = (zb == 0) ? w0 : (zb == 1) ? w1 : (zb == 2) ? w2 : w3;
  const bool i32 = (flg[0] != 0);
  const u16*   in16 = (const u16*)in_v;
  const float* in32 = (const float*)in_v;
  const int c0 = blockIdx.x * 32, r0 = blockIdx.y * 32;
  const int tx = threadIdx.x, ty = threadIdx.y;   // block (32,8)
  for (int i = ty; i < 32; i += 8) {
    const long idx = (long)(r0 + i) * D + c0 + tx;
    tile[i][tx] = i32 ? in32[idx] : bf2f(in16[idx]);
  }
  __syncthreads();
  f16* outH = (zb == 0) ? h0 : (zb == 1) ? h1 : h2;
  for (int i = ty; i < 32; i += 8) {
    const long idx = (long)(c0 + i) * D + r0 + tx;
    const float v = tile[tx][i];
    if (zb == 3) b3[idx]   = f2bf(v);
    else         outH[idx] = (f16)v;
  }
}

// ---------------- Q/K/V projections in one z=3 dispatch (fp16, BK=64) ----------------
// z=0: Qi@WqT+bq -> Qf (fp16). z=1: KVi@WkT+bk -> Kf (fp16).
// z=2: KVi@WvT+bv -> Vt (bf16, transposed [D][S] epilogue via staging-LDS bounce).
__global__ __launch_bounds__(256)
void gemm_proj3(const int* __restrict__ flg,
                const f16* __restrict__ Qi, const f16* __restrict__ KVi,
                const f16* __restrict__ WqT, const f16* __restrict__ WkT,
                const f16* __restrict__ WvT,
                const void* __restrict__ bq, const void* __restrict__ bk,
                const void* __restrict__ bv,
                f16* __restrict__ Qf, f16* __restrict__ Kf,
                u16* __restrict__ Vt, int M, int N, int K, int SB)
{
  __shared__ u16 As[BM * 64];   // two 128x32 subtiles: [0,4096) k0..31, [4096,8192) k32..63
  __shared__ u16 Bs[BN * 64];

  const int zb = blockIdx.z;
  const f16* A = (zb == 0) ? Qi : KVi;
  const f16* B = (zb == 0) ? WqT : (zb == 1) ? WkT : WvT;
  const void* bias = (zb == 0) ? bq : (zb == 1) ? bk : bv;

  const int f_in = flg[0];
  const int tid = threadIdx.x, lane = tid & 63, wave = tid >> 6;
  const int wm = wave >> 1, wn = wave & 1;
  const int m0 = blockIdx.y * BM, n0 = blockIdx.x * BN;

  const int rr  = wave * 32 + (lane >> 2);
  const int cc8 = (lane & 3) * 8;
  const f16* ga00 = A + (long)(m0 + rr) * K + cc8;
  const f16* ga01 = ga00 + 16 * (long)K;
  const f16* gb00 = B + (long)(n0 + rr) * K + cc8;
  const f16* gb01 = gb00 + 16 * (long)K;
  u16* la0 = &As[(wave * 2) * 512];  u16* la1 = la0 + 512;
  u16* lb0 = &Bs[(wave * 2) * 512];  u16* lb1 = lb0 + 512;

  f4v acc[4][4];
#pragma unroll
  for (int i = 0; i < 4; ++i)
#pragma unroll
    for (int j = 0; j < 4; ++j) acc[i][j] = (f4v){0.f, 0.f, 0.f, 0.f};

  const int fr = lane & 15, fk = (lane >> 4) * 8;
  const int aoff = (wm * 64 + fr) * 32 + fk;
  const int boff = (wn * 64 + fr) * 32 + fk;

  for (int kt = 0; kt < K; kt += 64) {
    glds16(ga00,      la0);        glds16(ga01,      la1);
    glds16(ga00 + 32, la0 + 4096); glds16(ga01 + 32, la1 + 4096);
    glds16(gb00,      lb0);        glds16(gb01,      lb1);
    glds16(gb00 + 32, lb0 + 4096); glds16(gb01 + 32, lb1 + 4096);
    ga00 += 64; ga01 += 64; gb00 += 64; gb01 += 64;
    __syncthreads();

    {
      h8v af[4], bfr[4];
#pragma unroll
      for (int mi = 0; mi < 4; ++mi) af[mi]  = *(const h8v*)&As[aoff + mi * 512];
#pragma unroll
      for (int ni = 0; ni < 4; ++ni) bfr[ni] = *(const h8v*)&Bs[boff + ni * 512];
#pragma unroll
      for (int mi = 0; mi < 4; ++mi)
#pragma unroll
        for (int ni = 0; ni < 4; ++ni)
          acc[mi][ni] = __builtin_amdgcn_mfma_f32_16x16x32_f16(af[mi], bfr[ni], acc[mi][ni], 0, 0, 0);
    }
    {
      h8v af[4], bfr[4];
#pragma unroll
      for (int mi = 0; mi < 4; ++mi) af[mi]  = *(const h8v*)&As[4096 + aoff + mi * 512];
#pragma unroll
      for (int ni = 0; ni < 4; ++ni) bfr[ni] = *(const h8v*)&Bs[4096 + boff + ni * 512];
#pragma unroll
      for (int mi = 0; mi < 4; ++mi)
#pragma unroll
        for (int ni = 0; ni < 4; ++ni)
          acc[mi][ni] = __builtin_amdgcn_mfma_f32_16x16x32_f16(af[mi], bfr[ni], acc[mi][ni], 0, 0, 0);
    }
    __syncthreads();
  }

  const int cr = (lane >> 4) * 4, ccl = lane & 15;
  if (zb < 2) {
    f16* out = zb ? Kf : Qf;
#pragma unroll
    for (int ni = 0; ni < 4; ++ni) {
      const int gcol = n0 + wn * 64 + ni * 16 + ccl;
      const float bvv = (f_in != 0) ? ((const float*)bias)[gcol]
                                    : bf2f(((const u16*)bias)[gcol]);
#pragma unroll
      for (int mi = 0; mi < 4; ++mi)
#pragma unroll
        for (int r = 0; r < 4; ++r) {
          const long grow = (long)(m0 + wm * 64 + mi * 16 + cr + r);
          out[grow * N + gcol] = (f16)(acc[mi][ni][r] + bvv);
        }
    }
  } else {
    // transposed epilogue through dead staging LDS (needs 4x2176 u16 <= As+Bs)
    u16* xw = (wave < 2) ? (&As[0] + wave * 2176) : (&Bs[0] + (wave - 2) * 2176);
    const int b  = m0 / SB;
    const int s0 = (m0 % SB) + wm * 64;
    const long bbase = (long)b * N * SB;
#pragma unroll
    for (int h = 0; h < 2; ++h) {
#pragma unroll
      for (int nl = 0; nl < 2; ++nl) {
        const int ni = h * 2 + nl;
        const int gcol = n0 + wn * 64 + ni * 16 + ccl;
        const float bvv = (f_in != 0) ? ((const float*)bias)[gcol]
                                      : bf2f(((const u16*)bias)[gcol]);
#pragma unroll
        for (int mi = 0; mi < 4; ++mi)
#pragma unroll
          for (int r = 0; r < 4; ++r)
            xw[(mi * 16 + cr + r) * 34 + nl * 16 + ccl] = f2bf(acc[mi][ni][r] + bvv);
      }
      __syncthreads();
#pragma unroll
      for (int c = 0; c < 32; ++c) {
        const int gcol = n0 + wn * 64 + h * 32 + c;
        Vt[bbase + (long)gcol * SB + s0 + lane] = xw[lane * 34 + c];
      }
      __syncthreads();
    }
  }
}

// ---------------- scores GEMM: fp16, BK=64, fp32 out, z-batched ----------------
__global__ __launch_bounds__(256)
void gemm_sc64(const f16* __restrict__ A, const f16* __restrict__ B,
               float* __restrict__ C, int M, int N, int K,
               long sA, long sB, long sC)
{
  __shared__ u16 As[BM * 64];
  __shared__ u16 Bs[BN * 64];

  const int tid = threadIdx.x, lane = tid & 63, wave = tid >> 6;
  const int wm = wave >> 1, wn = wave & 1;
  const int m0 = blockIdx.y * BM, n0 = blockIdx.x * BN;
  const long z = blockIdx.z;

  const int rr  = wave * 32 + (lane >> 2);
  const int cc8 = (lane & 3) * 8;
  const f16* ga00 = A + (long)(m0 + rr) * K + cc8 + z * sA;
  const f16* ga01 = ga00 + 16 * (long)K;
  const f16* gb00 = B + (long)(n0 + rr) * K + cc8 + z * sB;
  const f16* gb01 = gb00 + 16 * (long)K;
  u16* la0 = &As[(wave * 2) * 512];  u16* la1 = la0 + 512;
  u16* lb0 = &Bs[(wave * 2) * 512];  u16* lb1 = lb0 + 512;

  f4v acc[4][4];
#pragma unroll
  for (int i = 0; i < 4; ++i)
#pragma unroll
    for (int j = 0; j < 4; ++j) acc[i][j] = (f4v){0.f, 0.f, 0.f, 0.f};

  const int fr = lane & 15, fk = (lane >> 4) * 8;
  const int aoff = (wm * 64 + fr) * 32 + fk;
  const int boff = (wn * 64 + fr) * 32 + fk;

  for (int kt = 0; kt < K; kt += 64) {
    glds16(ga00,      la0);        glds16(ga01,      la1);
    glds16(ga00 + 32, la0 + 4096); glds16(ga01 + 32, la1 + 4096);
    glds16(gb00,      lb0);        glds16(gb01,      lb1);
    glds16(gb00 + 32, lb0 + 4096); glds16(gb01 + 32, lb1 + 4096);
    ga00 += 64; ga01 += 64; gb00 += 64; gb01 += 64;
    __syncthreads();

    {
      h8v af[4], bfr[4];
#pragma unroll
      for (int mi = 0; mi < 4; ++mi) af[mi]  = *(const h8v*)&As[aoff + mi * 512];
#pragma unroll
      for (int ni = 0; ni < 4; ++ni) bfr[ni] = *(const h8v*)&Bs[boff + ni * 512];
#pragma unroll
      for (int mi = 0; mi < 4; ++mi)
#pragma unroll
        for (int ni = 0; ni < 4; ++ni)
          acc[mi][ni] = __builtin_amdgcn_mfma_f32_16x16x32_f16(af[mi], bfr[ni], acc[mi][ni], 0, 0, 0);
    }
    {
      h8v af[4], bfr[4];
#pragma unroll
      for (int mi = 0; mi < 4; ++mi) af[mi]  = *(const h8v*)&As[4096 + aoff + mi * 512];
#pragma unroll
      for (int ni = 0; ni < 4; ++ni) bfr[ni] = *(const h8v*)&Bs[4096 + boff + ni * 512];
#pragma unroll
      for (int mi = 0; mi < 4; ++mi)
#pragma unroll
        for (int ni = 0; ni < 4; ++ni)
          acc[mi][ni] = __builtin_amdgcn_mfma_f32_16x16x32_f16(af[mi], bfr[ni], acc[mi][ni], 0, 0, 0);
    }
    __syncthreads();
  }

  const int cr = (lane >> 4) * 4, ccl = lane & 15;
#pragma unroll
  for (int ni = 0; ni < 4; ++ni) {
    const int gcol = n0 + wn * 64 + ni * 16 + ccl;
#pragma unroll
    for (int mi = 0; mi < 4; ++mi)
#pragma unroll
      for (int r = 0; r < 4; ++r) {
        const long grow = (long)(m0 + wm * 64 + mi * 16 + cr + r);
        C[z * sC + grow * N + gcol] = acc[mi][ni][r];
      }
  }
}

// ---------------- bf16 NT GEMM, BK=64 (PV, out-proj) ----------------
template<bool OUT_FLAG, bool HAS_BIAS>
__global__ __launch_bounds__(256)
void gemm_bf64(const int* __restrict__ flg, const u16* __restrict__ A,
               const u16* __restrict__ Bt, const void* __restrict__ bias,
               void* __restrict__ Cv, int M, int N, int K,
               long sA, long sB, long sC)
{
  __shared__ u16 As[BM * 64];
  __shared__ u16 Bs[BN * 64];

  const int f_in = flg[0];
  const int tid = threadIdx.x, lane = tid & 63, wave = tid >> 6;
  const int wm = wave >> 1, wn = wave & 1;
  const int m0 = blockIdx.y * BM, n0 = blockIdx.x * BN;
  const long z = blockIdx.z;

  const int rr  = wave * 32 + (lane >> 2);
  const int cc8 = (lane & 3) * 8;
  const u16* ga00 = A + (long)(m0 + rr) * K + cc8 + z * sA;
  const u16* ga01 = ga00 + 16 * (long)K;
  const u16* gb00 = Bt + (long)(n0 + rr) * K + cc8 + z * sB;
  const u16* gb01 = gb00 + 16 * (long)K;
  u16* la0 = &As[(wave * 2) * 512];  u16* la1 = la0 + 512;
  u16* lb0 = &Bs[(wave * 2) * 512];  u16* lb1 = lb0 + 512;

  f4v acc[4][4];
#pragma unroll
  for (int i = 0; i < 4; ++i)
#pragma unroll
    for (int j = 0; j < 4; ++j) acc[i][j] = (f4v){0.f, 0.f, 0.f, 0.f};

  const int fr = lane & 15, fk = (lane >> 4) * 8;
  const int aoff = (wm * 64 + fr) * 32 + fk;
  const int boff = (wn * 64 + fr) * 32 + fk;

  for (int kt = 0; kt < K; kt += 64) {
    glds16(ga00,      la0);        glds16(ga01,      la1);
    glds16(ga00 + 32, la0 + 4096); glds16(ga01 + 32, la1 + 4096);
    glds16(gb00,      lb0);        glds16(gb01,      lb1);
    glds16(gb00 + 32, lb0 + 4096); glds16(gb01 + 32, lb1 + 4096);
    ga00 += 64; ga01 += 64; gb00 += 64; gb01 += 64;
    __syncthreads();

    {
      s8v af[4], bfr[4];
#pragma unroll
      for (int mi = 0; mi < 4; ++mi) af[mi]  = *(const s8v*)&As[aoff + mi * 512];
#pragma unroll
      for (int ni = 0; ni < 4; ++ni) bfr[ni] = *(const s8v*)&Bs[boff + ni * 512];
#pragma unroll
      for (int mi = 0; mi < 4; ++mi)
#pragma unroll
        for (int ni = 0; ni < 4; ++ni)
          acc[mi][ni] = __builtin_amdgcn_mfma_f32_16x16x32_bf16(af[mi], bfr[ni], acc[mi][ni], 0, 0, 0);
    }
    {
      s8v af[4], bfr[4];
#pragma unroll
      for (int mi = 0; mi < 4; ++mi) af[mi]  = *(const s8v*)&As[4096 + aoff + mi * 512];
#pragma unroll
      for (int ni = 0; ni < 4; ++ni) bfr[ni] = *(const s8v*)&Bs[4096 + boff + ni * 512];
#pragma unroll
      for (int mi = 0; mi < 4; ++mi)
#pragma unroll
        for (int ni = 0; ni < 4; ++ni)
          acc[mi][ni] = __builtin_amdgcn_mfma_f32_16x16x32_bf16(af[mi], bfr[ni], acc[mi][ni], 0, 0, 0);
    }
    __syncthreads();
  }

  const int cr = (lane >> 4) * 4, ccl = lane & 15;
  const bool o32 = OUT_FLAG && (f_in != 0);
#pragma unroll
  for (int ni = 0; ni < 4; ++ni) {
    const int gcol = n0 + wn * 64 + ni * 16 + ccl;
    float bvv = 0.f;
    if (HAS_BIAS)
      bvv = (f_in != 0) ? ((const float*)bias)[gcol] : bf2f(((const u16*)bias)[gcol]);
#pragma unroll
    for (int mi = 0; mi < 4; ++mi)
#pragma unroll
      for (int r = 0; r < 4; ++r) {
        const long grow = (long)(m0 + wm * 64 + mi * 16 + cr + r);
        const float val = acc[mi][ni][r] + bvv;
        const long idx = z * sC + grow * N + gcol;
        if (o32) ((float*)Cv)[idx] = val;
        else     ((u16*)Cv)[idx]   = f2bf(val);
      }
  }
}

// ---------------- row softmax fp32 -> bf16 attn, N=2048, one block/row ----------------
__global__ __launch_bounds__(256)
void softmax_rows_bf(const float* __restrict__ S, u16* __restrict__ P, int N)
{
  const float* row = S + (long)blockIdx.x * N;
  u16* prow = P + (long)blockIdx.x * N;
  const int t = threadIdx.x;
  f4v v0 = *(const f4v*)(row + t * 8);
  f4v v1 = *(const f4v*)(row + t * 8 + 4);

  float m = v0[0];
#pragma unroll
  for (int j = 1; j < 4; ++j) m = fmaxf(m, v0[j]);
#pragma unroll
  for (int j = 0; j < 4; ++j) m = fmaxf(m, v1[j]);
  for (int off = 32; off > 0; off >>= 1) m = fmaxf(m, __shfl_down(m, off, 64));

  __shared__ float redm[4], reds[4];
  if ((t & 63) == 0) redm[t >> 6] = m;
  __syncthreads();
  m = fmaxf(fmaxf(redm[0], redm[1]), fmaxf(redm[2], redm[3]));

  float s = 0.f;
#pragma unroll
  for (int j = 0; j < 4; ++j) { v0[j] = __expf(v0[j] - m); s += v0[j]; }
#pragma unroll
  for (int j = 0; j < 4; ++j) { v1[j] = __expf(v1[j] - m); s += v1[j]; }
  for (int off = 32; off > 0; off >>= 1) s += __shfl_down(s, off, 64);
  if ((t & 63) == 0) reds[t >> 6] = s;
  __syncthreads();
  s = reds[0] + reds[1] + reds[2] + reds[3];

  const float inv = 1.f / s;
  s8v o;
#pragma unroll
  for (int j = 0; j < 4; ++j) {
    o[j]     = (short)f2bf(v0[j] * inv);
    o[4 + j] = (short)f2bf(v1[j] * inv);
  }
  *(s8v*)(prow + t * 8) = o;
}

extern "C" void kernel_launch(void* const* d_in, const int* in_sizes, int n_in,
                              void* d_out, int out_size, void* d_ws, size_t ws_size,
                              hipStream_t stream)
{
  const void* query = d_in[0];
  const void* kv    = d_in[1];
  const void* Wq    = d_in[2];
  const void* bq    = d_in[3];
  const void* Wk    = d_in[4];
  const void* bk    = d_in[5];
  const void* Wv    = d_in[6];
  const void* bv    = d_in[7];
  const void* Wo    = d_in[8];
  const void* bo    = d_in[9];

  const int Bn = 4, S = 2048, D = 1024;
  const int MS = Bn * S;                       // 8192
  const size_t KBu = 1024, MBu = 1024 * 1024;
  const long nTok = (long)MS * D;

  // ---- workspace layout (~168 MB; ws proven >= 173 MB) ----
  char* ws = (char*)d_ws;
  int*  flg  = (int*)(ws);
  f16*  Qi   = (f16*)(ws + 64 * KBu);          // 16MB fp16 input tokens
  f16*  KVi  = (f16*)(ws + 64 * KBu + 16 * MBu);
  char* rW   = ws + 64 * KBu + 32 * MBu;       // 8MB: W^T
  f16*  WqT  = (f16*)(rW);
  f16*  WkT  = (f16*)(rW + 2 * MBu);
  f16*  WvT  = (f16*)(rW + 4 * MBu);
  u16*  WoT  = (u16*)(rW + 6 * MBu);
  char* rQK  = rW + 8 * MBu;                   // 32MB: Q,K fp16; later attn bf16
  f16*  Qf   = (f16*)(rQK);
  f16*  Kf   = (f16*)(rQK + 16 * MBu);
  u16*  attn = (u16*)(rQK);                    // 32MB (Q/K dead after scores)
  float* Sc  = (float*)(rQK + 32 * MBu);       // 64MB fp32 scores
  char* rV   = rQK + 96 * MBu;                 // 32MB
  u16*  Vt   = (u16*)(rV);                     // [B][D][S] bf16
  u16*  Cx   = (u16*)(rV + 16 * MBu);          // [B][S][D] bf16

  detect_dtype<<<1, 256, 0, stream>>>((const u16*)query, flg);

  convert_h<<<dim3((unsigned)(nTok / 2048), 2), 256, 0, stream>>>(
      flg, query, kv, Qi, KVi, nTok);

  dim3 tb(32, 8);
  transpose_w4<<<dim3(32, 32, 4), tb, 0, stream>>>(
      flg, Wq, Wk, Wv, Wo, WqT, WkT, WvT, WoT, D);

  // Q, K, V projections in one dispatch (V -> Vt transposed)
  gemm_proj3<<<dim3(D / BN, MS / BM, 3), 256, 0, stream>>>(
      flg, Qi, KVi, WqT, WkT, WvT, bq, bk, bv, Qf, Kf, Vt, MS, D, D, S);

  // scores (fp16, fp32 out), softmax -> bf16 attn, PV (bf16)
  gemm_sc64<<<dim3(S / BN, S / BM, Bn), 256, 0, stream>>>(
      Qf, Kf, Sc, S, S, D, (long)S * D, (long)S * D, (long)S * S);
  softmax_rows_bf<<<dim3(Bn * S), 256, 0, stream>>>(Sc, attn, S);
  gemm_bf64<false, false><<<dim3(D / BN, S / BM, Bn), 256, 0, stream>>>(
      flg, attn, Vt, nullptr, Cx, S, D, S, (long)S * S, (long)D * S, (long)S * D);

  // output projection -> d_out (dtype per flag)
  gemm_bf64<true, true><<<dim3(D / BN, MS / BM, 1), 256, 0, stream>>>(
      flg, Cx, WoT, bo, d_out, MS, D, D, 0L, 0L, 0L);
}